// Round 1
// baseline (7515.586 us; speedup 1.0000x reference)
//
#include <hip/hip_runtime.h>

#define B_    16
#define CIN   100
#define T_    1024
#define CH_   512
#define HCH_  1536
#define NL_   8
#define NFFT_ 1024
#define HOP_  256
#define K_    4
#define BT    (B_ * T_)
#define L_    (T_ + K_ - 1)   // 1027

// ---------------- in conv: x[b,ci,t] (pad 3, 7 taps) -> h[b,t,c] (+bias) ----
__global__ __launch_bounds__(256) void k_inconv(const float* __restrict__ x,
                                                const float* __restrict__ w,
                                                const float* __restrict__ bias,
                                                float* __restrict__ h) {
  int b  = blockIdx.x;
  int t0 = blockIdx.y * 16;
  __shared__ float xs[CIN][22];
  for (int e = threadIdx.x; e < CIN * 22; e += 256) {
    int i = e / 22, dt = e % 22;
    int t = t0 - 3 + dt;
    xs[i][dt] = (t >= 0 && t < T_) ? x[(b * CIN + i) * T_ + t] : 0.f;
  }
  __syncthreads();
  for (int c = threadIdx.x; c < CH_; c += 256) {
    float acc[16];
#pragma unroll
    for (int t = 0; t < 16; ++t) acc[t] = 0.f;
    const float* wc = w + c * CIN * 7;
    for (int i = 0; i < CIN; ++i) {
      float xv[22];
#pragma unroll
      for (int d = 0; d < 22; ++d) xv[d] = xs[i][d];
      float wk[7];
#pragma unroll
      for (int k = 0; k < 7; ++k) wk[k] = wc[i * 7 + k];
#pragma unroll
      for (int t = 0; t < 16; ++t) {
        float a = 0.f;
#pragma unroll
        for (int k = 0; k < 7; ++k) a += xv[t + k] * wk[k];
        acc[t] += a;
      }
    }
    float bb = bias[c];
#pragma unroll
    for (int t = 0; t < 16; ++t) h[((b * T_ + t0 + t) * CH_) + c] = acc[t] + bb;
  }
}

// ---------------- layernorm over channel (in place), torch semantics --------
__global__ __launch_bounds__(256) void k_ln(float* __restrict__ p,
                                            const float* __restrict__ g,
                                            const float* __restrict__ bta) {
  int row = blockIdx.x;
  float* pr = p + (size_t)row * CH_;
  int tid = threadIdx.x;
  float v0 = pr[tid], v1 = pr[tid + 256];
  float s = v0 + v1, q = v0 * v0 + v1 * v1;
#pragma unroll
  for (int o = 32; o > 0; o >>= 1) {
    s += __shfl_down(s, o);
    q += __shfl_down(q, o);
  }
  __shared__ float sh[8];
  int wid = tid >> 6, lane = tid & 63;
  if (lane == 0) { sh[wid] = s; sh[wid + 4] = q; }
  __syncthreads();
  float S = sh[0] + sh[1] + sh[2] + sh[3];
  float Q = sh[4] + sh[5] + sh[6] + sh[7];
  float mu  = S * (1.f / 512.f);
  float var = Q * (1.f / 512.f) - mu * mu;
  float r = rsqrtf(var + 1e-5f);
  pr[tid]       = (v0 - mu) * r * g[tid]       + bta[tid];
  pr[tid + 256] = (v1 - mu) * r * g[tid + 256] + bta[tid + 256];
}

// ---------------- depthwise 7-tap conv over t: h[b,t,c] -> y[b,t,c] ---------
__global__ __launch_bounds__(256) void k_dw(const float* __restrict__ h,
                                            const float* __restrict__ w,
                                            const float* __restrict__ bias,
                                            float* __restrict__ y) {
  int bt = blockIdx.x;
  int b = bt >> 10, t = bt & 1023;
  int c = threadIdx.x;
#pragma unroll
  for (int cc = 0; cc < 2; ++cc, c += 256) {
    float acc = bias[c];
#pragma unroll
    for (int k = 0; k < 7; ++k) {
      int tt = t + k - 3;
      if (tt >= 0 && tt < T_) acc += h[((size_t)((b << 10) + tt)) * CH_ + c] * w[c * 7 + k];
    }
    y[(size_t)bt * CH_ + c] = acc;
  }
}

// ---------------- generic fp32 GEMM: OUT[m,n] = sum_k A[m,k]*Bw[n,k] --------
// MODE 0: out = acc + bias  |  MODE 1: out = gelu(acc+bias)
// MODE 2: res[m,n] += (acc + bias[n]) * scale[n]
template <int MODE>
__global__ __launch_bounds__(256) void k_gemm(const float* __restrict__ A,
                                              const float* __restrict__ Bw,
                                              const float* __restrict__ bias,
                                              const float* __restrict__ scale,
                                              float* __restrict__ out,
                                              float* __restrict__ res,
                                              int M, int N, int Kd) {
  __shared__ float As[16][68];
  __shared__ float Bs[16][68];
  int m0 = blockIdx.x * 64, n0 = blockIdx.y * 64;
  int tid = threadIdx.x;
  int tx = tid & 15, ty = tid >> 4;   // tx -> n, ty -> m
  float acc[4][4] = {};
  int lk = tid & 15, lm = tid >> 4;
  for (int k0 = 0; k0 < Kd; k0 += 16) {
#pragma unroll
    for (int p = 0; p < 4; ++p) {
      As[lk][lm + p * 16] = A[(size_t)(m0 + lm + p * 16) * Kd + k0 + lk];
      Bs[lk][lm + p * 16] = Bw[(size_t)(n0 + lm + p * 16) * Kd + k0 + lk];
    }
    __syncthreads();
#pragma unroll
    for (int kk = 0; kk < 16; ++kk) {
      float4 av = *reinterpret_cast<const float4*>(&As[kk][ty * 4]);
      float4 bv = *reinterpret_cast<const float4*>(&Bs[kk][tx * 4]);
      float a[4] = {av.x, av.y, av.z, av.w};
      float b[4] = {bv.x, bv.y, bv.z, bv.w};
#pragma unroll
      for (int i = 0; i < 4; ++i)
#pragma unroll
        for (int j = 0; j < 4; ++j) acc[i][j] += a[i] * b[j];
    }
    __syncthreads();
  }
#pragma unroll
  for (int i = 0; i < 4; ++i) {
    int m = m0 + ty * 4 + i;
    int nb = n0 + tx * 4;
    if (MODE == 2) {
      float4 r = *reinterpret_cast<float4*>(&res[(size_t)m * N + nb]);
      r.x += (acc[i][0] + bias[nb + 0]) * scale[nb + 0];
      r.y += (acc[i][1] + bias[nb + 1]) * scale[nb + 1];
      r.z += (acc[i][2] + bias[nb + 2]) * scale[nb + 2];
      r.w += (acc[i][3] + bias[nb + 3]) * scale[nb + 3];
      *reinterpret_cast<float4*>(&res[(size_t)m * N + nb]) = r;
    } else {
      float v[4];
#pragma unroll
      for (int j = 0; j < 4; ++j) {
        v[j] = acc[i][j] + bias[nb + j];
        if (MODE == 1) v[j] = 0.5f * v[j] * (1.f + erff(v[j] * 0.70710678118654752440f));
      }
      float4 o = {v[0], v[1], v[2], v[3]};
      *reinterpret_cast<float4*>(&out[(size_t)m * N + nb]) = o;
    }
  }
}

// ---------------- overlap conv: o2[b,c,l] = sum_{n,k} o1[b,l+k-3,n]*w[c,n,k]
__global__ __launch_bounds__(256) void k_ovconv(const float* __restrict__ o1,  // [b][t][n]
                                                const float* __restrict__ w,   // [256][1024][4]
                                                float* __restrict__ o2) {      // [b][256][1027]
  int b = blockIdx.x, c0 = blockIdx.y * 64, l0 = blockIdx.z * 64;
  __shared__ float Xs[16][68];   // [n][l-l0+3], 67 used
  __shared__ float Ws[64][64];   // [c][nn*4+k]
  int tid = threadIdx.x;
  int tx = tid & 15, ty = tid >> 4;   // tx -> l, ty -> c
  float acc[4][4] = {};
  for (int n0 = 0; n0 < NFFT_; n0 += 16) {
    for (int e = tid; e < 16 * 67; e += 256) {
      int nl = e / 67, dl = e % 67;
      int l = l0 - 3 + dl;
      Xs[nl][dl] = (l >= 0 && l < T_) ? o1[((size_t)b * T_ + l) * NFFT_ + n0 + nl] : 0.f;
    }
    for (int e = tid; e < 64 * 64; e += 256) {
      int cc = e >> 6, f = e & 63;
      Ws[cc][f] = w[((size_t)(c0 + cc)) * (NFFT_ * 4) + n0 * 4 + f];
    }
    __syncthreads();
#pragma unroll
    for (int nn = 0; nn < 16; ++nn) {
#pragma unroll
      for (int k = 0; k < 4; ++k) {
        float wv[4], xv[4];
#pragma unroll
        for (int i = 0; i < 4; ++i) wv[i] = Ws[ty * 4 + i][nn * 4 + k];
#pragma unroll
        for (int j = 0; j < 4; ++j) xv[j] = Xs[nn][tx * 4 + j + k];
#pragma unroll
        for (int i = 0; i < 4; ++i)
#pragma unroll
          for (int j = 0; j < 4; ++j) acc[i][j] += wv[i] * xv[j];
      }
    }
    __syncthreads();
  }
#pragma unroll
  for (int i = 0; i < 4; ++i) {
    int c = c0 + ty * 4 + i;
#pragma unroll
    for (int j = 0; j < 4; ++j) {
      int l = l0 + tx * 4 + j;
      if (l < L_) o2[((size_t)b * HOP_ + c) * L_ + l] = acc[i][j];
    }
  }
}

// ---------------- final gather-sum: out[b,t] = sum_c o2[b,c,(t+2-4c) mod L] -
__global__ __launch_bounds__(256) void k_oadd(const float* __restrict__ o2,
                                              float* __restrict__ out) {
  int b = blockIdx.x;
  int t = blockIdx.y * 256 + threadIdx.x;
  float s = 0.f;
  for (int c = 0; c < HOP_; ++c) {
    int m = (t + 2 - 4 * c) % L_;
    if (m < 0) m += L_;
    s += o2[((size_t)b * HOP_ + c) * L_ + m];
  }
  out[b * T_ + t] = s;
}

extern "C" void kernel_launch(void* const* d_in, const int* in_sizes, int n_in,
                              void* d_out, int out_size, void* d_ws, size_t ws_size,
                              hipStream_t stream) {
  const float* x      = (const float*)d_in[0];
  const float* in_w   = (const float*)d_in[1];
  const float* in_b   = (const float*)d_in[2];
  const float* norm_g = (const float*)d_in[3];
  const float* norm_b = (const float*)d_in[4];
  const float* dw_w   = (const float*)d_in[5];
  const float* dw_b   = (const float*)d_in[6];
  const float* ln_g   = (const float*)d_in[7];
  const float* ln_b   = (const float*)d_in[8];
  const float* pw1_w  = (const float*)d_in[9];
  const float* pw1_b  = (const float*)d_in[10];
  const float* pw2_w  = (const float*)d_in[11];
  const float* pw2_b  = (const float*)d_in[12];
  const float* ls     = (const float*)d_in[13];
  const float* normLg = (const float*)d_in[14];
  const float* normLb = (const float*)d_in[15];
  const float* out_w  = (const float*)d_in[16];   // [1024][512][1]
  const float* out_b  = (const float*)d_in[17];
  const float* ov_w   = (const float*)d_in[18];   // [256][1024][4]
  float* out = (float*)d_out;

  float* h  = (float*)d_ws;                 //  8,388,608 f
  float* y  = h + (size_t)BT * CH_;         //  8,388,608 f
  float* z  = y + (size_t)BT * CH_;         // 25,165,824 f
  float* o1 = z;                            // alias (z free after layers)
  float* o2 = y;                            // alias (y free after layers)

  k_inconv<<<dim3(B_, T_ / 16), 256, 0, stream>>>(x, in_w, in_b, h);
  k_ln<<<BT, 256, 0, stream>>>(h, norm_g, norm_b);
  for (int l = 0; l < NL_; ++l) {
    k_dw<<<BT, 256, 0, stream>>>(h, dw_w + (size_t)l * CH_ * 7, dw_b + l * CH_, y);
    k_ln<<<BT, 256, 0, stream>>>(y, ln_g + l * CH_, ln_b + l * CH_);
    k_gemm<1><<<dim3(BT / 64, HCH_ / 64), 256, 0, stream>>>(
        y, pw1_w + (size_t)l * HCH_ * CH_, pw1_b + l * HCH_, nullptr, z, nullptr,
        BT, HCH_, CH_);
    k_gemm<2><<<dim3(BT / 64, CH_ / 64), 256, 0, stream>>>(
        z, pw2_w + (size_t)l * CH_ * HCH_, pw2_b + l * CH_, ls + l * CH_, nullptr, h,
        BT, CH_, HCH_);
  }
  k_ln<<<BT, 256, 0, stream>>>(h, normLg, normLb);
  k_gemm<0><<<dim3(BT / 64, NFFT_ / 64), 256, 0, stream>>>(
      h, out_w, out_b, nullptr, o1, nullptr, BT, NFFT_, CH_);
  k_ovconv<<<dim3(B_, HOP_ / 64, (L_ + 63) / 64), 256, 0, stream>>>(o1, ov_w, o2);
  k_oadd<<<dim3(B_, T_ / 256), 256, 0, stream>>>(o2, out);
}

// Round 2
// 1624.845 us; speedup vs baseline: 4.6254x; 4.6254x over previous
//
#include <hip/hip_runtime.h>

#define B_    16
#define CIN   100
#define T_    1024
#define CH_   512
#define HCH_  1536
#define NL_   8
#define NFFT_ 1024
#define HOP_  256
#define BT    (B_ * T_)
#define L_    1027
#define OROWS 1032   // padded o1 rows per batch: [4 zero | 1024 data | 4 zero]

typedef __bf16 bf16x8 __attribute__((ext_vector_type(8)));
typedef float f32x4 __attribute__((ext_vector_type(4)));

__device__ __forceinline__ short f2b(float f) {
  unsigned u = __float_as_uint(f);
  u += 0x7fffu + ((u >> 16) & 1u);
  return (short)(u >> 16);
}

__device__ __forceinline__ void gl2lds16(const void* g, void* l) {
  __builtin_amdgcn_global_load_lds(
      (__attribute__((address_space(1))) void*)g,
      (__attribute__((address_space(3))) void*)l, 16, 0, 0);
}

// ---------------- weight fp32 -> bf16 (contiguous) --------------------------
__global__ __launch_bounds__(256) void k_cvt(const float* __restrict__ s,
                                             short* __restrict__ d, int n) {
  for (int i = blockIdx.x * 256 + threadIdx.x; i < n; i += gridDim.x * 256)
    d[i] = f2b(s[i]);
}

// ov_w[c][n][k] -> ovb[k][c][n] bf16
__global__ __launch_bounds__(256) void k_cvt_ov(const float* __restrict__ w,
                                                short* __restrict__ d) {
  const int n = 4 * HOP_ * NFFT_;
  for (int i = blockIdx.x * 256 + threadIdx.x; i < n; i += gridDim.x * 256) {
    int k = i >> 18;
    int rem = i & 0x3FFFF;
    int c = rem >> 10, nn = rem & 1023;
    d[i] = f2b(w[((size_t)c * NFFT_ + nn) * 4 + k]);
  }
}

// zero the 4+4 pad rows of o1p per batch
__global__ __launch_bounds__(256) void k_zeropad(short* __restrict__ o1p) {
  int i = blockIdx.x * 256 + threadIdx.x;  // 16*8*1024 = 131072
  int b = i >> 13;
  int r8 = (i >> 10) & 7;
  int nn = i & 1023;
  int row = r8 < 4 ? r8 : (OROWS - 8 + r8);
  o1p[((size_t)b * OROWS + row) * NFFT_ + nn] = 0;
}

// ---------------- in conv: x[b,ci,t] (pad 3, 7 taps) -> h[b,t,c] fp32 -------
__global__ __launch_bounds__(256) void k_inconv(const float* __restrict__ x,
                                                const float* __restrict__ w,
                                                const float* __restrict__ bias,
                                                float* __restrict__ h) {
  int b  = blockIdx.x;
  int t0 = blockIdx.y * 16;
  __shared__ float xs[CIN][22];
  for (int e = threadIdx.x; e < CIN * 22; e += 256) {
    int i = e / 22, dt = e % 22;
    int t = t0 - 3 + dt;
    xs[i][dt] = (t >= 0 && t < T_) ? x[(b * CIN + i) * T_ + t] : 0.f;
  }
  __syncthreads();
  for (int c = threadIdx.x; c < CH_; c += 256) {
    float acc[16];
#pragma unroll
    for (int t = 0; t < 16; ++t) acc[t] = 0.f;
    const float* wc = w + c * CIN * 7;
    for (int i = 0; i < CIN; ++i) {
      float xv[22];
#pragma unroll
      for (int d = 0; d < 22; ++d) xv[d] = xs[i][d];
      float wk[7];
#pragma unroll
      for (int k = 0; k < 7; ++k) wk[k] = wc[i * 7 + k];
#pragma unroll
      for (int t = 0; t < 16; ++t) {
        float a = 0.f;
#pragma unroll
        for (int k = 0; k < 7; ++k) a += xv[t + k] * wk[k];
        acc[t] += a;
      }
    }
    float bb = bias[c];
#pragma unroll
    for (int t = 0; t < 16; ++t) h[((b * T_ + t0 + t) * CH_) + c] = acc[t] + bb;
  }
}

// ---------------- layernorm fp32 in-place (first LN) ------------------------
__global__ __launch_bounds__(256) void k_ln(float* __restrict__ p,
                                            const float* __restrict__ g,
                                            const float* __restrict__ bta) {
  int row = blockIdx.x;
  float* pr = p + (size_t)row * CH_;
  int tid = threadIdx.x;
  float v0 = pr[tid], v1 = pr[tid + 256];
  float s = v0 + v1, q = v0 * v0 + v1 * v1;
#pragma unroll
  for (int o = 32; o > 0; o >>= 1) { s += __shfl_down(s, o); q += __shfl_down(q, o); }
  __shared__ float sh[8];
  int wid = tid >> 6, lane = tid & 63;
  if (lane == 0) { sh[wid] = s; sh[wid + 4] = q; }
  __syncthreads();
  float S = sh[0] + sh[1] + sh[2] + sh[3];
  float Q = sh[4] + sh[5] + sh[6] + sh[7];
  float mu  = S * (1.f / 512.f);
  float var = Q * (1.f / 512.f) - mu * mu;
  float r = rsqrtf(var + 1e-5f);
  pr[tid]       = (v0 - mu) * r * g[tid]       + bta[tid];
  pr[tid + 256] = (v1 - mu) * r * g[tid + 256] + bta[tid + 256];
}

// ---------------- final layernorm: h fp32 -> hb bf16 ------------------------
__global__ __launch_bounds__(256) void k_ln_bf16(const float* __restrict__ p,
                                                 const float* __restrict__ g,
                                                 const float* __restrict__ bta,
                                                 short* __restrict__ ob) {
  int row = blockIdx.x;
  const float* pr = p + (size_t)row * CH_;
  int tid = threadIdx.x;
  float v0 = pr[tid], v1 = pr[tid + 256];
  float s = v0 + v1, q = v0 * v0 + v1 * v1;
#pragma unroll
  for (int o = 32; o > 0; o >>= 1) { s += __shfl_down(s, o); q += __shfl_down(q, o); }
  __shared__ float sh[8];
  int wid = tid >> 6, lane = tid & 63;
  if (lane == 0) { sh[wid] = s; sh[wid + 4] = q; }
  __syncthreads();
  float S = sh[0] + sh[1] + sh[2] + sh[3];
  float Q = sh[4] + sh[5] + sh[6] + sh[7];
  float mu  = S * (1.f / 512.f);
  float var = Q * (1.f / 512.f) - mu * mu;
  float r = rsqrtf(var + 1e-5f);
  ob[(size_t)row * CH_ + tid]       = f2b((v0 - mu) * r * g[tid]       + bta[tid]);
  ob[(size_t)row * CH_ + tid + 256] = f2b((v1 - mu) * r * g[tid + 256] + bta[tid + 256]);
}

// ---------------- fused depthwise 7-tap + layernorm -> yb bf16 --------------
__global__ __launch_bounds__(256) void k_dwln(const float* __restrict__ h,
                                              const float* __restrict__ dww,
                                              const float* __restrict__ dwb,
                                              const float* __restrict__ g,
                                              const float* __restrict__ bta,
                                              short* __restrict__ yb) {
  int bt = blockIdx.x;
  int b = bt >> 10, t = bt & 1023;
  int tid = threadIdx.x;
  float v[2];
#pragma unroll
  for (int cc = 0; cc < 2; ++cc) {
    int c = tid + cc * 256;
    float acc = dwb[c];
#pragma unroll
    for (int k = 0; k < 7; ++k) {
      int tt = t + k - 3;
      if (tt >= 0 && tt < T_) acc += h[((size_t)((b << 10) + tt)) * CH_ + c] * dww[c * 7 + k];
    }
    v[cc] = acc;
  }
  float s = v[0] + v[1], q = v[0] * v[0] + v[1] * v[1];
#pragma unroll
  for (int o = 32; o > 0; o >>= 1) { s += __shfl_down(s, o); q += __shfl_down(q, o); }
  __shared__ float sh[8];
  int wid = tid >> 6, lane = tid & 63;
  if (lane == 0) { sh[wid] = s; sh[wid + 4] = q; }
  __syncthreads();
  float S = sh[0] + sh[1] + sh[2] + sh[3];
  float Q = sh[4] + sh[5] + sh[6] + sh[7];
  float mu  = S * (1.f / 512.f);
  float var = Q * (1.f / 512.f) - mu * mu;
  float rr = rsqrtf(var + 1e-5f);
#pragma unroll
  for (int cc = 0; cc < 2; ++cc) {
    int c = tid + cc * 256;
    yb[(size_t)bt * CH_ + c] = f2b((v[cc] - mu) * rr * g[c] + bta[c]);
  }
}

// ---------------- bf16 MFMA GEMM: C[m,n] = sum_k A[m,k]*Bw[n,k] -------------
// 128x128 tile, BK=64, 4 waves, 4x4 frags of 16x16x32.
// MODE 1: obf = bf16(gelu(acc+bias))        [M][N]
// MODE 2: res[m][n] += (acc+bias)*scale     fp32
// MODE 3: obf = bf16(acc+bias) at padded o1 rows (b*OROWS+4+t)
template <int MODE>
__global__ __launch_bounds__(256) void k_mgemm(const short* __restrict__ A,
                                               const short* __restrict__ Bw,
                                               const float* __restrict__ bias,
                                               const float* __restrict__ scale,
                                               short* __restrict__ obf,
                                               float* __restrict__ res,
                                               int M, int N, int K) {
  __shared__ __align__(16) short As[128 * 64];
  __shared__ __align__(16) short Bs[128 * 64];
  const int tid = threadIdx.x;
  const int lane = tid & 63, w = tid >> 6;
  const int m0 = blockIdx.x * 128, n0 = blockIdx.y * 128;
  const int wr = (w >> 1) * 64, wc = (w & 1) * 64;
  f32x4 acc[4][4];
#pragma unroll
  for (int i = 0; i < 4; ++i)
#pragma unroll
    for (int j = 0; j < 4; ++j) acc[i][j] = (f32x4){0.f, 0.f, 0.f, 0.f};

  const short* Ab = A + (size_t)m0 * K;
  const short* Bb = Bw + (size_t)n0 * K;
  int r_[4], kk_[4];
#pragma unroll
  for (int j = 0; j < 4; ++j) {
    int c = tid + j * 256;
    r_[j] = c >> 3;
    kk_[j] = (((c & 7) ^ (r_[j] & 7)) * 8);   // inverse-swizzled source (rule #21)
  }
  short* AsB[4]; short* BsB[4];
#pragma unroll
  for (int j = 0; j < 4; ++j) {
    AsB[j] = As + (j * 256 + w * 64) * 8;
    BsB[j] = Bs + (j * 256 + w * 64) * 8;
  }
  const int ar = wr + (lane & 15);
  const int br = wc + (lane & 15);
  const int hi = lane >> 4;

  for (int k0 = 0; k0 < K; k0 += 64) {
#pragma unroll
    for (int j = 0; j < 4; ++j) gl2lds16(Ab + (size_t)r_[j] * K + k0 + kk_[j], AsB[j]);
#pragma unroll
    for (int j = 0; j < 4; ++j) gl2lds16(Bb + (size_t)r_[j] * K + k0 + kk_[j], BsB[j]);
    asm volatile("s_waitcnt vmcnt(0)" ::: "memory");
    __syncthreads();
#pragma unroll
    for (int ks = 0; ks < 2; ++ks) {
      bf16x8 a[4], b[4];
#pragma unroll
      for (int f = 0; f < 4; ++f) {
        int row = ar + f * 16;
        a[f] = *reinterpret_cast<const bf16x8*>(&As[row * 64 + (((ks * 4 + hi) ^ (row & 7)) * 8)]);
      }
#pragma unroll
      for (int f = 0; f < 4; ++f) {
        int row = br + f * 16;
        b[f] = *reinterpret_cast<const bf16x8*>(&Bs[row * 64 + (((ks * 4 + hi) ^ (row & 7)) * 8)]);
      }
#pragma unroll
      for (int fi = 0; fi < 4; ++fi)
#pragma unroll
        for (int fj = 0; fj < 4; ++fj)
          acc[fi][fj] = __builtin_amdgcn_mfma_f32_16x16x32_bf16(a[fi], b[fj], acc[fi][fj], 0, 0, 0);
    }
    __syncthreads();
  }
  // epilogue: D row = (lane>>4)*4 + reg, col = lane&15
  const int mb = m0 + wr + (hi << 2);
  const int nb = n0 + wc + (lane & 15);
#pragma unroll
  for (int fj = 0; fj < 4; ++fj) {
    int n = nb + fj * 16;
    float bi = bias[n];
    float sc = (MODE == 2) ? scale[n] : 0.f;
#pragma unroll
    for (int fi = 0; fi < 4; ++fi) {
      int mrow = mb + fi * 16;
#pragma unroll
      for (int r = 0; r < 4; ++r) {
        float v = acc[fi][fj][r] + bi;
        int m = mrow + r;
        if (MODE == 1) {
          v = 0.5f * v * (1.f + erff(v * 0.70710678118654752440f));
          obf[(size_t)m * N + n] = f2b(v);
        } else if (MODE == 2) {
          res[(size_t)m * N + n] += v * sc;
        } else {
          int bb = m >> 10, t = m & 1023;
          obf[((size_t)(bb * OROWS + 4 + t)) * NFFT_ + n] = f2b(v);
        }
      }
    }
  }
}

// ---------------- overlap conv as 4 shift-accumulated MFMA GEMMs ------------
// o2[b][l][c] = sum_{k=0..3} sum_n o1p[b][l+1+k][n] * ovb[k][c][n]
__global__ __launch_bounds__(256) void k_ovgemm(const short* __restrict__ o1p,
                                                const short* __restrict__ ovb,
                                                float* __restrict__ o2) {
  __shared__ __align__(16) short As[128 * 64];
  __shared__ __align__(16) short Bs[128 * 64];
  const int tid = threadIdx.x;
  const int lane = tid & 63, w = tid >> 6;
  const int l0 = blockIdx.x * 128, c0 = blockIdx.y * 128, b = blockIdx.z;
  const int wr = (w >> 1) * 64, wc = (w & 1) * 64;
  f32x4 acc[4][4];
#pragma unroll
  for (int i = 0; i < 4; ++i)
#pragma unroll
    for (int j = 0; j < 4; ++j) acc[i][j] = (f32x4){0.f, 0.f, 0.f, 0.f};

  const short* Ab = o1p + (size_t)b * OROWS * NFFT_;
  int r_[4], kk_[4];
#pragma unroll
  for (int j = 0; j < 4; ++j) {
    int c = tid + j * 256;
    r_[j] = c >> 3;
    kk_[j] = (((c & 7) ^ (r_[j] & 7)) * 8);
  }
  short* AsB[4]; short* BsB[4];
#pragma unroll
  for (int j = 0; j < 4; ++j) {
    AsB[j] = As + (j * 256 + w * 64) * 8;
    BsB[j] = Bs + (j * 256 + w * 64) * 8;
  }
  const int ar = wr + (lane & 15);
  const int br = wc + (lane & 15);
  const int hi = lane >> 4;

  for (int ksh = 0; ksh < 4; ++ksh) {
    const short* Bb = ovb + ((size_t)(ksh * HOP_ + c0)) * NFFT_;
    for (int k0 = 0; k0 < NFFT_; k0 += 64) {
#pragma unroll
      for (int j = 0; j < 4; ++j) {
        int tp = l0 + r_[j] + 1 + ksh;
        tp = tp > (OROWS - 1) ? (OROWS - 1) : tp;   // clamp into zero pad
        gl2lds16(Ab + (size_t)tp * NFFT_ + k0 + kk_[j], AsB[j]);
      }
#pragma unroll
      for (int j = 0; j < 4; ++j) gl2lds16(Bb + (size_t)r_[j] * NFFT_ + k0 + kk_[j], BsB[j]);
      asm volatile("s_waitcnt vmcnt(0)" ::: "memory");
      __syncthreads();
#pragma unroll
      for (int ks = 0; ks < 2; ++ks) {
        bf16x8 a[4], bfr[4];
#pragma unroll
        for (int f = 0; f < 4; ++f) {
          int row = ar + f * 16;
          a[f] = *reinterpret_cast<const bf16x8*>(&As[row * 64 + (((ks * 4 + hi) ^ (row & 7)) * 8)]);
        }
#pragma unroll
        for (int f = 0; f < 4; ++f) {
          int row = br + f * 16;
          bfr[f] = *reinterpret_cast<const bf16x8*>(&Bs[row * 64 + (((ks * 4 + hi) ^ (row & 7)) * 8)]);
        }
#pragma unroll
        for (int fi = 0; fi < 4; ++fi)
#pragma unroll
          for (int fj = 0; fj < 4; ++fj)
            acc[fi][fj] = __builtin_amdgcn_mfma_f32_16x16x32_bf16(a[fi], bfr[fj], acc[fi][fj], 0, 0, 0);
      }
      __syncthreads();
    }
  }
  const int lb = l0 + wr + (hi << 2);
  const int cb = c0 + wc + (lane & 15);
#pragma unroll
  for (int fj = 0; fj < 4; ++fj) {
    int c = cb + fj * 16;
#pragma unroll
    for (int fi = 0; fi < 4; ++fi) {
#pragma unroll
      for (int r = 0; r < 4; ++r) {
        int l = lb + fi * 16 + r;
        if (l < L_) o2[((size_t)b * L_ + l) * HOP_ + c] = acc[fi][fj][r];
      }
    }
  }
}

// ---------------- final gather-sum over o2[b][l][c] -------------------------
__global__ __launch_bounds__(256) void k_oadd(const float* __restrict__ o2,
                                              float* __restrict__ out) {
  int b = blockIdx.x;
  int t = blockIdx.y * 256 + threadIdx.x;
  int m = t + 2;
  float s = 0.f;
  for (int c = 0; c < HOP_; ++c) {
    s += o2[((size_t)b * L_ + m) * HOP_ + c];
    m -= 4;
    if (m < 0) m += L_;
  }
  out[b * T_ + t] = s;
}

extern "C" void kernel_launch(void* const* d_in, const int* in_sizes, int n_in,
                              void* d_out, int out_size, void* d_ws, size_t ws_size,
                              hipStream_t stream) {
  const float* x      = (const float*)d_in[0];
  const float* in_w   = (const float*)d_in[1];
  const float* in_b   = (const float*)d_in[2];
  const float* norm_g = (const float*)d_in[3];
  const float* norm_b = (const float*)d_in[4];
  const float* dw_w   = (const float*)d_in[5];
  const float* dw_b   = (const float*)d_in[6];
  const float* ln_g   = (const float*)d_in[7];
  const float* ln_b   = (const float*)d_in[8];
  const float* pw1_w  = (const float*)d_in[9];
  const float* pw1_b  = (const float*)d_in[10];
  const float* pw2_w  = (const float*)d_in[11];
  const float* pw2_b  = (const float*)d_in[12];
  const float* ls     = (const float*)d_in[13];
  const float* normLg = (const float*)d_in[14];
  const float* normLb = (const float*)d_in[15];
  const float* out_w  = (const float*)d_in[16];
  const float* out_b  = (const float*)d_in[17];
  const float* ov_w   = (const float*)d_in[18];
  float* out = (float*)d_out;

  char* p = (char*)d_ws;
  float* h    = (float*)p;  p += (size_t)BT * CH_ * 4;        // 33.5 MB
  short* yb   = (short*)p;  p += (size_t)BT * CH_ * 2;        // 16.8 MB
  short* zb   = (short*)p;  p += (size_t)BT * HCH_ * 2;       // 50.3 MB
  short* pw1b = (short*)p;  p += (size_t)NL_ * HCH_ * CH_ * 2;
  short* pw2b = (short*)p;  p += (size_t)NL_ * CH_ * HCH_ * 2;
  short* owb  = (short*)p;  p += (size_t)NFFT_ * CH_ * 2;
  short* ovb  = (short*)p;  p += (size_t)4 * HOP_ * NFFT_ * 2;
  short* hb   = yb;   // alias: yb dead after layer loop
  short* o1p  = zb;   // alias: zb dead after layer loop (33.8 MB <= 50.3 MB)
  float* o2   = h;    // alias: h dead after final LN

  k_cvt<<<4096, 256, 0, stream>>>(pw1_w, pw1b, NL_ * HCH_ * CH_);
  k_cvt<<<4096, 256, 0, stream>>>(pw2_w, pw2b, NL_ * CH_ * HCH_);
  k_cvt<<<2048, 256, 0, stream>>>(out_w, owb, NFFT_ * CH_);
  k_cvt_ov<<<4096, 256, 0, stream>>>(ov_w, ovb);

  k_inconv<<<dim3(B_, T_ / 16), 256, 0, stream>>>(x, in_w, in_b, h);
  k_ln<<<BT, 256, 0, stream>>>(h, norm_g, norm_b);
  for (int l = 0; l < NL_; ++l) {
    k_dwln<<<BT, 256, 0, stream>>>(h, dw_w + (size_t)l * CH_ * 7, dw_b + l * CH_,
                                   ln_g + l * CH_, ln_b + l * CH_, yb);
    k_mgemm<1><<<dim3(128, 12), 256, 0, stream>>>(
        yb, pw1b + (size_t)l * HCH_ * CH_, pw1_b + l * HCH_, nullptr, zb, nullptr,
        BT, HCH_, CH_);
    k_mgemm<2><<<dim3(128, 4), 256, 0, stream>>>(
        zb, pw2b + (size_t)l * CH_ * HCH_, pw2_b + l * CH_, ls + l * CH_, nullptr, h,
        BT, CH_, HCH_);
  }
  k_ln_bf16<<<BT, 256, 0, stream>>>(h, normLg, normLb, hb);
  k_mgemm<3><<<dim3(128, 8), 256, 0, stream>>>(
      hb, owb, out_b, nullptr, o1p, nullptr, BT, NFFT_, CH_);
  k_zeropad<<<512, 256, 0, stream>>>(o1p);
  k_ovgemm<<<dim3(9, 2, 16), 256, 0, stream>>>(o1p, ovb, o2);
  k_oadd<<<dim3(B_, 4), 256, 0, stream>>>(o2, out);
}

// Round 3
// 1271.022 us; speedup vs baseline: 5.9130x; 1.2784x over previous
//
#include <hip/hip_runtime.h>

#define B_    16
#define CIN   100
#define T_    1024
#define CH_   512
#define HCH_  1536
#define NL_   8
#define NFFT_ 1024
#define HOP_  256
#define BT    (B_ * T_)
#define L_    1027
#define OROWS 1032   // padded o1 rows per batch: [4 zero | 1024 data | 4 zero]
#define KIN   704    // im2col K for in-conv (100*7 -> pad 704)

typedef __bf16 bf16x8 __attribute__((ext_vector_type(8)));
typedef float f32x4 __attribute__((ext_vector_type(4)));

__device__ __forceinline__ short f2b(float f) {
  unsigned u = __float_as_uint(f);
  u += 0x7fffu + ((u >> 16) & 1u);
  return (short)(u >> 16);
}

__device__ __forceinline__ void gl2lds16(const void* g, void* l) {
  __builtin_amdgcn_global_load_lds(
      (__attribute__((address_space(1))) void*)g,
      (__attribute__((address_space(3))) void*)l, 16, 0, 0);
}

// ---------------- weight fp32 -> bf16 (contiguous) --------------------------
__global__ __launch_bounds__(256) void k_cvt(const float* __restrict__ s,
                                             short* __restrict__ d, int n) {
  for (int i = blockIdx.x * 256 + threadIdx.x; i < n; i += gridDim.x * 256)
    d[i] = f2b(s[i]);
}

// ov_w[c][n][k] -> ovb[k][c][n] bf16
__global__ __launch_bounds__(256) void k_cvt_ov(const float* __restrict__ w,
                                                short* __restrict__ d) {
  const int n = 4 * HOP_ * NFFT_;
  for (int i = blockIdx.x * 256 + threadIdx.x; i < n; i += gridDim.x * 256) {
    int k = i >> 18;
    int rem = i & 0x3FFFF;
    int c = rem >> 10, nn = rem & 1023;
    d[i] = f2b(w[((size_t)c * NFFT_ + nn) * 4 + k]);
  }
}

// in_w[c][ci][k] (700 contiguous per c) -> wib[c][704] bf16, pad 0
__global__ __launch_bounds__(256) void k_cvt_inw(const float* __restrict__ w,
                                                 short* __restrict__ d) {
  const int n = CH_ * KIN;
  for (int i = blockIdx.x * 256 + threadIdx.x; i < n; i += gridDim.x * 256) {
    int c = i / KIN, e = i - c * KIN;
    d[i] = (e < 700) ? f2b(w[c * 700 + e]) : (short)0;
  }
}

// x[b][ci][t] fp32 -> xim[b*T+t][ci*7+k] = x[b,ci,t+k-3] bf16 (0 pad)
__global__ __launch_bounds__(256) void k_im2col(const float* __restrict__ x,
                                                short* __restrict__ xim) {
  const int total = BT * KIN;
  for (int i = blockIdx.x * 256 + threadIdx.x; i < total; i += gridDim.x * 256) {
    int m = i / KIN, e = i - m * KIN;
    int b = m >> 10, t = m & 1023;
    int ci = e / 7, k = e - ci * 7;
    int tt = t + k - 3;
    float v = (e < 700 && tt >= 0 && tt < T_) ? x[((b * CIN + ci) << 10) + tt] : 0.f;
    xim[i] = f2b(v);
  }
}

// zero the 4+4 pad rows of o1p per batch
__global__ __launch_bounds__(256) void k_zeropad(short* __restrict__ o1p) {
  int i = blockIdx.x * 256 + threadIdx.x;  // 16*8*1024 = 131072
  int b = i >> 13;
  int r8 = (i >> 10) & 7;
  int nn = i & 1023;
  int row = r8 < 4 ? r8 : (OROWS - 8 + r8);
  o1p[((size_t)b * OROWS + row) * NFFT_ + nn] = 0;
}

// ---------------- layernorm fp32 in-place (first LN) ------------------------
__global__ __launch_bounds__(256) void k_ln(float* __restrict__ p,
                                            const float* __restrict__ g,
                                            const float* __restrict__ bta) {
  int row = blockIdx.x;
  float* pr = p + (size_t)row * CH_;
  int tid = threadIdx.x;
  float v0 = pr[tid], v1 = pr[tid + 256];
  float s = v0 + v1, q = v0 * v0 + v1 * v1;
#pragma unroll
  for (int o = 32; o > 0; o >>= 1) { s += __shfl_down(s, o); q += __shfl_down(q, o); }
  __shared__ float sh[8];
  int wid = tid >> 6, lane = tid & 63;
  if (lane == 0) { sh[wid] = s; sh[wid + 4] = q; }
  __syncthreads();
  float S = sh[0] + sh[1] + sh[2] + sh[3];
  float Q = sh[4] + sh[5] + sh[6] + sh[7];
  float mu  = S * (1.f / 512.f);
  float var = Q * (1.f / 512.f) - mu * mu;
  float r = rsqrtf(var + 1e-5f);
  pr[tid]       = (v0 - mu) * r * g[tid]       + bta[tid];
  pr[tid + 256] = (v1 - mu) * r * g[tid + 256] + bta[tid + 256];
}

// ---------------- final layernorm: h fp32 -> hb bf16 ------------------------
__global__ __launch_bounds__(256) void k_ln_bf16(const float* __restrict__ p,
                                                 const float* __restrict__ g,
                                                 const float* __restrict__ bta,
                                                 short* __restrict__ ob) {
  int row = blockIdx.x;
  const float* pr = p + (size_t)row * CH_;
  int tid = threadIdx.x;
  float v0 = pr[tid], v1 = pr[tid + 256];
  float s = v0 + v1, q = v0 * v0 + v1 * v1;
#pragma unroll
  for (int o = 32; o > 0; o >>= 1) { s += __shfl_down(s, o); q += __shfl_down(q, o); }
  __shared__ float sh[8];
  int wid = tid >> 6, lane = tid & 63;
  if (lane == 0) { sh[wid] = s; sh[wid + 4] = q; }
  __syncthreads();
  float S = sh[0] + sh[1] + sh[2] + sh[3];
  float Q = sh[4] + sh[5] + sh[6] + sh[7];
  float mu  = S * (1.f / 512.f);
  float var = Q * (1.f / 512.f) - mu * mu;
  float r = rsqrtf(var + 1e-5f);
  ob[(size_t)row * CH_ + tid]       = f2b((v0 - mu) * r * g[tid]       + bta[tid]);
  ob[(size_t)row * CH_ + tid + 256] = f2b((v1 - mu) * r * g[tid + 256] + bta[tid + 256]);
}

// ---------------- fused depthwise 7-tap + LN, t-tiled (32 rows/block) -------
__global__ __launch_bounds__(256) void k_dwln(const float* __restrict__ h,
                                              const float* __restrict__ dww,
                                              const float* __restrict__ dwb,
                                              const float* __restrict__ g,
                                              const float* __restrict__ bta,
                                              short* __restrict__ yb) {
  int b = blockIdx.x, t0 = blockIdx.y * 32;
  int tid = threadIdx.x;
  __shared__ float hs[38][512];
  __shared__ float sh[2][8];
  // stage 38 rows (t0-3 .. t0+34) x 512 ch, fp32, coalesced float4
  for (int e = tid; e < 38 * 128; e += 256) {
    int row = e >> 7, c4 = (e & 127) << 2;
    int t = t0 - 3 + row;
    float4 v = {0.f, 0.f, 0.f, 0.f};
    if (t >= 0 && t < T_)
      v = *reinterpret_cast<const float4*>(&h[((size_t)((b << 10) + t)) * CH_ + c4]);
    *reinterpret_cast<float4*>(&hs[row][c4]) = v;
  }
  float wk0[7], wk1[7];
#pragma unroll
  for (int k = 0; k < 7; ++k) {
    wk0[k] = dww[tid * 7 + k];
    wk1[k] = dww[(tid + 256) * 7 + k];
  }
  float b0 = dwb[tid], b1 = dwb[tid + 256];
  float g0 = g[tid], g1 = g[tid + 256];
  float be0 = bta[tid], be1 = bta[tid + 256];
  int wid = tid >> 6, lane = tid & 63;
  __syncthreads();
  for (int r = 0; r < 32; ++r) {
    float v0 = b0, v1 = b1;
#pragma unroll
    for (int k = 0; k < 7; ++k) {
      v0 += hs[r + k][tid] * wk0[k];
      v1 += hs[r + k][tid + 256] * wk1[k];
    }
    float s = v0 + v1, q = v0 * v0 + v1 * v1;
#pragma unroll
    for (int o = 32; o > 0; o >>= 1) { s += __shfl_down(s, o); q += __shfl_down(q, o); }
    int pb = r & 1;
    if (lane == 0) { sh[pb][wid] = s; sh[pb][wid + 4] = q; }
    __syncthreads();
    float S = sh[pb][0] + sh[pb][1] + sh[pb][2] + sh[pb][3];
    float Q = sh[pb][4] + sh[pb][5] + sh[pb][6] + sh[pb][7];
    float mu  = S * (1.f / 512.f);
    float var = Q * (1.f / 512.f) - mu * mu;
    float rr = rsqrtf(var + 1e-5f);
    size_t o0 = (size_t)((b << 10) + t0 + r) * CH_;
    yb[o0 + tid]       = f2b((v0 - mu) * rr * g0 + be0);
    yb[o0 + tid + 256] = f2b((v1 - mu) * rr * g1 + be1);
  }
}

// ---------------- bf16 MFMA GEMM: C[m,n] = sum_k A[m,k]*Bw[n,k] -------------
// 128x128 tile, BK=64, 4 waves, 4x4 frags of 16x16x32. M is always 16384.
// Flattened 1D grid, bijective XCD swizzle; m-tiles fastest (nx=128).
// MODE 0: res = acc + bias (fp32)
// MODE 1: obf = bf16(gelu(acc+bias))
// MODE 2: res[m][n] += (acc+bias)*scale     fp32
// MODE 3: obf = bf16(acc+bias) at padded o1 rows (b*OROWS+4+t)
template <int MODE>
__global__ __launch_bounds__(256) void k_mgemm(const short* __restrict__ A,
                                               const short* __restrict__ Bw,
                                               const float* __restrict__ bias,
                                               const float* __restrict__ scale,
                                               short* __restrict__ obf,
                                               float* __restrict__ res,
                                               int M, int N, int K) {
  __shared__ __align__(16) short As[128 * 64];
  __shared__ __align__(16) short Bs[128 * 64];
  const int tid = threadIdx.x;
  const int lane = tid & 63, w = tid >> 6;
  const int nwg = gridDim.x;
  const int id = blockIdx.x;
  const int sw = ((id & 7) * (nwg >> 3)) + (id >> 3);   // nwg % 8 == 0 always
  const int m0 = (sw & 127) << 7;                        // nx = 16384/128 = 128
  const int n0 = (sw >> 7) << 7;
  const int wr = (w >> 1) * 64, wc = (w & 1) * 64;
  f32x4 acc[4][4];
#pragma unroll
  for (int i = 0; i < 4; ++i)
#pragma unroll
    for (int j = 0; j < 4; ++j) acc[i][j] = (f32x4){0.f, 0.f, 0.f, 0.f};

  const short* Ab = A + (size_t)m0 * K;
  const short* Bb = Bw + (size_t)n0 * K;
  int r_[4], kk_[4];
#pragma unroll
  for (int j = 0; j < 4; ++j) {
    int c = tid + j * 256;
    r_[j] = c >> 3;
    kk_[j] = (((c & 7) ^ (r_[j] & 7)) * 8);   // inverse-swizzled source (rule #21)
  }
  short* AsB[4]; short* BsB[4];
#pragma unroll
  for (int j = 0; j < 4; ++j) {
    AsB[j] = As + (j * 256 + w * 64) * 8;
    BsB[j] = Bs + (j * 256 + w * 64) * 8;
  }
  const int ar = wr + (lane & 15);
  const int br = wc + (lane & 15);
  const int hi = lane >> 4;

  for (int k0 = 0; k0 < K; k0 += 64) {
#pragma unroll
    for (int j = 0; j < 4; ++j) gl2lds16(Ab + (size_t)r_[j] * K + k0 + kk_[j], AsB[j]);
#pragma unroll
    for (int j = 0; j < 4; ++j) gl2lds16(Bb + (size_t)r_[j] * K + k0 + kk_[j], BsB[j]);
    asm volatile("s_waitcnt vmcnt(0)" ::: "memory");
    __syncthreads();
#pragma unroll
    for (int ks = 0; ks < 2; ++ks) {
      bf16x8 a[4], b[4];
#pragma unroll
      for (int f = 0; f < 4; ++f) {
        int row = ar + f * 16;
        a[f] = *reinterpret_cast<const bf16x8*>(&As[row * 64 + (((ks * 4 + hi) ^ (row & 7)) * 8)]);
      }
#pragma unroll
      for (int f = 0; f < 4; ++f) {
        int row = br + f * 16;
        b[f] = *reinterpret_cast<const bf16x8*>(&Bs[row * 64 + (((ks * 4 + hi) ^ (row & 7)) * 8)]);
      }
#pragma unroll
      for (int fi = 0; fi < 4; ++fi)
#pragma unroll
        for (int fj = 0; fj < 4; ++fj)
          acc[fi][fj] = __builtin_amdgcn_mfma_f32_16x16x32_bf16(a[fi], b[fj], acc[fi][fj], 0, 0, 0);
    }
    __syncthreads();
  }
  // epilogue: D row = (lane>>4)*4 + reg, col = lane&15
  const int mb = m0 + wr + (hi << 2);
  const int nb = n0 + wc + (lane & 15);
#pragma unroll
  for (int fj = 0; fj < 4; ++fj) {
    int n = nb + fj * 16;
    float bi = bias[n];
    float sc = (MODE == 2) ? scale[n] : 0.f;
#pragma unroll
    for (int fi = 0; fi < 4; ++fi) {
      int mrow = mb + fi * 16;
#pragma unroll
      for (int r = 0; r < 4; ++r) {
        float v = acc[fi][fj][r] + bi;
        int m = mrow + r;
        if (MODE == 0) {
          res[(size_t)m * N + n] = v;
        } else if (MODE == 1) {
          v = 0.5f * v * (1.f + erff(v * 0.70710678118654752440f));
          obf[(size_t)m * N + n] = f2b(v);
        } else if (MODE == 2) {
          res[(size_t)m * N + n] += v * sc;
        } else {
          int bb = m >> 10, t = m & 1023;
          obf[((size_t)(bb * OROWS + 4 + t)) * NFFT_ + n] = f2b(v);
        }
      }
    }
  }
}

// ---------------- overlap conv as 4 shift-accumulated MFMA GEMMs ------------
// o2[b][l][c] = sum_{k=0..3} sum_n o1p[b][l+1+k][n] * ovb[k][c][n]
__global__ __launch_bounds__(256) void k_ovgemm(const short* __restrict__ o1p,
                                                const short* __restrict__ ovb,
                                                float* __restrict__ o2) {
  __shared__ __align__(16) short As[128 * 64];
  __shared__ __align__(16) short Bs[128 * 64];
  const int tid = threadIdx.x;
  const int lane = tid & 63, w = tid >> 6;
  const int l0 = blockIdx.x * 128, c0 = blockIdx.y * 128, b = blockIdx.z;
  const int wr = (w >> 1) * 64, wc = (w & 1) * 64;
  f32x4 acc[4][4];
#pragma unroll
  for (int i = 0; i < 4; ++i)
#pragma unroll
    for (int j = 0; j < 4; ++j) acc[i][j] = (f32x4){0.f, 0.f, 0.f, 0.f};

  const short* Ab = o1p + (size_t)b * OROWS * NFFT_;
  int r_[4], kk_[4];
#pragma unroll
  for (int j = 0; j < 4; ++j) {
    int c = tid + j * 256;
    r_[j] = c >> 3;
    kk_[j] = (((c & 7) ^ (r_[j] & 7)) * 8);
  }
  short* AsB[4]; short* BsB[4];
#pragma unroll
  for (int j = 0; j < 4; ++j) {
    AsB[j] = As + (j * 256 + w * 64) * 8;
    BsB[j] = Bs + (j * 256 + w * 64) * 8;
  }
  const int ar = wr + (lane & 15);
  const int br = wc + (lane & 15);
  const int hi = lane >> 4;

  for (int ksh = 0; ksh < 4; ++ksh) {
    const short* Bb = ovb + ((size_t)(ksh * HOP_ + c0)) * NFFT_;
    for (int k0 = 0; k0 < NFFT_; k0 += 64) {
#pragma unroll
      for (int j = 0; j < 4; ++j) {
        int tp = l0 + r_[j] + 1 + ksh;
        tp = tp > (OROWS - 1) ? (OROWS - 1) : tp;   // clamp into zero pad
        gl2lds16(Ab + (size_t)tp * NFFT_ + k0 + kk_[j], AsB[j]);
      }
#pragma unroll
      for (int j = 0; j < 4; ++j) gl2lds16(Bb + (size_t)r_[j] * NFFT_ + k0 + kk_[j], BsB[j]);
      asm volatile("s_waitcnt vmcnt(0)" ::: "memory");
      __syncthreads();
#pragma unroll
      for (int ks = 0; ks < 2; ++ks) {
        bf16x8 a[4], bfr[4];
#pragma unroll
        for (int f = 0; f < 4; ++f) {
          int row = ar + f * 16;
          a[f] = *reinterpret_cast<const bf16x8*>(&As[row * 64 + (((ks * 4 + hi) ^ (row & 7)) * 8)]);
        }
#pragma unroll
        for (int f = 0; f < 4; ++f) {
          int row = br + f * 16;
          bfr[f] = *reinterpret_cast<const bf16x8*>(&Bs[row * 64 + (((ks * 4 + hi) ^ (row & 7)) * 8)]);
        }
#pragma unroll
        for (int fi = 0; fi < 4; ++fi)
#pragma unroll
          for (int fj = 0; fj < 4; ++fj)
            acc[fi][fj] = __builtin_amdgcn_mfma_f32_16x16x32_bf16(a[fi], bfr[fj], acc[fi][fj], 0, 0, 0);
      }
      __syncthreads();
    }
  }
  const int lb = l0 + wr + (hi << 2);
  const int cb = c0 + wc + (lane & 15);
#pragma unroll
  for (int fj = 0; fj < 4; ++fj) {
    int c = cb + fj * 16;
#pragma unroll
    for (int fi = 0; fi < 4; ++fi) {
#pragma unroll
      for (int r = 0; r < 4; ++r) {
        int l = lb + fi * 16 + r;
        if (l < L_) o2[((size_t)b * L_ + l) * HOP_ + c] = acc[fi][fj][r];
      }
    }
  }
}

// ---------------- final gather-sum over o2[b][l][c] -------------------------
__global__ __launch_bounds__(256) void k_oadd(const float* __restrict__ o2,
                                              float* __restrict__ out) {
  int b = blockIdx.x;
  int t = blockIdx.y * 256 + threadIdx.x;
  int m = t + 2;
  float s = 0.f;
  for (int c = 0; c < HOP_; ++c) {
    s += o2[((size_t)b * L_ + m) * HOP_ + c];
    m -= 4;
    if (m < 0) m += L_;
  }
  out[b * T_ + t] = s;
}

extern "C" void kernel_launch(void* const* d_in, const int* in_sizes, int n_in,
                              void* d_out, int out_size, void* d_ws, size_t ws_size,
                              hipStream_t stream) {
  const float* x      = (const float*)d_in[0];
  const float* in_w   = (const float*)d_in[1];
  const float* in_b   = (const float*)d_in[2];
  const float* norm_g = (const float*)d_in[3];
  const float* norm_b = (const float*)d_in[4];
  const float* dw_w   = (const float*)d_in[5];
  const float* dw_b   = (const float*)d_in[6];
  const float* ln_g   = (const float*)d_in[7];
  const float* ln_b   = (const float*)d_in[8];
  const float* pw1_w  = (const float*)d_in[9];
  const float* pw1_b  = (const float*)d_in[10];
  const float* pw2_w  = (const float*)d_in[11];
  const float* pw2_b  = (const float*)d_in[12];
  const float* ls     = (const float*)d_in[13];
  const float* normLg = (const float*)d_in[14];
  const float* normLb = (const float*)d_in[15];
  const float* out_w  = (const float*)d_in[16];
  const float* out_b  = (const float*)d_in[17];
  const float* ov_w   = (const float*)d_in[18];
  float* out = (float*)d_out;

  char* p = (char*)d_ws;
  float* h    = (float*)p;  p += (size_t)BT * CH_ * 4;        // 33.5 MB
  short* yb   = (short*)p;  p += (size_t)BT * CH_ * 2;        // 16.8 MB
  short* zb   = (short*)p;  p += (size_t)BT * HCH_ * 2;       // 50.3 MB
  short* pw1b = (short*)p;  p += (size_t)NL_ * HCH_ * CH_ * 2;
  short* pw2b = (short*)p;  p += (size_t)NL_ * CH_ * HCH_ * 2;
  short* owb  = (short*)p;  p += (size_t)NFFT_ * CH_ * 2;
  short* ovb  = (short*)p;  p += (size_t)4 * HOP_ * NFFT_ * 2;
  short* xim  = zb;                        // alias: zb not yet used
  short* wib  = zb + (size_t)BT * KIN;     // alias: fits in zb (11.9M < 25.2M shorts)
  short* hb   = yb;   // alias: yb dead after layer loop
  short* o1p  = zb;   // alias: zb dead after layer loop
  float* o2   = h;    // alias: h dead after final LN

  k_cvt<<<4096, 256, 0, stream>>>(pw1_w, pw1b, NL_ * HCH_ * CH_);
  k_cvt<<<4096, 256, 0, stream>>>(pw2_w, pw2b, NL_ * CH_ * HCH_);
  k_cvt<<<2048, 256, 0, stream>>>(out_w, owb, NFFT_ * CH_);
  k_cvt_ov<<<4096, 256, 0, stream>>>(ov_w, ovb);
  k_cvt_inw<<<1408, 256, 0, stream>>>(in_w, wib);
  k_im2col<<<8192, 256, 0, stream>>>(x, xim);

  k_mgemm<0><<<512, 256, 0, stream>>>(xim, wib, in_b, nullptr, nullptr, h,
                                      BT, CH_, KIN);
  k_ln<<<BT, 256, 0, stream>>>(h, norm_g, norm_b);
  for (int l = 0; l < NL_; ++l) {
    k_dwln<<<dim3(B_, T_ / 32), 256, 0, stream>>>(
        h, dw_w + (size_t)l * CH_ * 7, dw_b + l * CH_,
        ln_g + l * CH_, ln_b + l * CH_, yb);
    k_mgemm<1><<<1536, 256, 0, stream>>>(
        yb, pw1b + (size_t)l * HCH_ * CH_, pw1_b + l * HCH_, nullptr, zb, nullptr,
        BT, HCH_, CH_);
    k_mgemm<2><<<512, 256, 0, stream>>>(
        zb, pw2b + (size_t)l * CH_ * HCH_, pw2_b + l * CH_, ls + l * CH_, nullptr, h,
        BT, CH_, HCH_);
  }
  k_ln_bf16<<<BT, 256, 0, stream>>>(h, normLg, normLb, hb);
  k_mgemm<3><<<1024, 256, 0, stream>>>(
      hb, owb, out_b, nullptr, o1p, nullptr, BT, NFFT_, CH_);
  k_zeropad<<<512, 256, 0, stream>>>(o1p);
  k_ovgemm<<<dim3(9, 2, 16), 256, 0, stream>>>(o1p, ovb, o2);
  k_oadd<<<dim3(B_, 4), 256, 0, stream>>>(o2, out);
}

// Round 4
// 1044.220 us; speedup vs baseline: 7.1973x; 1.2172x over previous
//
#include <hip/hip_runtime.h>

#define B_    16
#define CIN   100
#define T_    1024
#define CH_   512
#define HCH_  1536
#define NL_   8
#define NFFT_ 1024
#define HOP_  256
#define BT    (B_ * T_)
#define L_    1027
#define OROWS 1032   // padded o1 rows per batch: [4 zero | 1024 data | 4 zero]
#define KIN   704    // im2col K for in-conv (100*7 -> pad 704)

typedef __bf16 bf16x8 __attribute__((ext_vector_type(8)));
typedef float f32x4 __attribute__((ext_vector_type(4)));
typedef short s16x8 __attribute__((ext_vector_type(8)));

__device__ __forceinline__ short f2b(float f) {
  unsigned u = __float_as_uint(f);
  u += 0x7fffu + ((u >> 16) & 1u);
  return (short)(u >> 16);
}
__device__ __forceinline__ float b2f(short s) {
  return __uint_as_float(((unsigned)(unsigned short)s) << 16);
}

__device__ __forceinline__ void gl2lds16(const void* g, void* l) {
  __builtin_amdgcn_global_load_lds(
      (__attribute__((address_space(1))) void*)g,
      (__attribute__((address_space(3))) void*)l, 16, 0, 0);
}

// ---------------- weight fp32 -> bf16 (contiguous) --------------------------
__global__ __launch_bounds__(256) void k_cvt(const float* __restrict__ s,
                                             short* __restrict__ d, int n) {
  for (int i = blockIdx.x * 256 + threadIdx.x; i < n; i += gridDim.x * 256)
    d[i] = f2b(s[i]);
}

// ov_w[c][n][k] -> ovb[k][c][n] bf16
__global__ __launch_bounds__(256) void k_cvt_ov(const float* __restrict__ w,
                                                short* __restrict__ d) {
  const int n = 4 * HOP_ * NFFT_;
  for (int i = blockIdx.x * 256 + threadIdx.x; i < n; i += gridDim.x * 256) {
    int k = i >> 18;
    int rem = i & 0x3FFFF;
    int c = rem >> 10, nn = rem & 1023;
    d[i] = f2b(w[((size_t)c * NFFT_ + nn) * 4 + k]);
  }
}

// in_w[c][ci][k] (700 contiguous per c) -> wib[c][704] bf16, pad 0
__global__ __launch_bounds__(256) void k_cvt_inw(const float* __restrict__ w,
                                                 short* __restrict__ d) {
  const int n = CH_ * KIN;
  for (int i = blockIdx.x * 256 + threadIdx.x; i < n; i += gridDim.x * 256) {
    int c = i / KIN, e = i - c * KIN;
    d[i] = (e < 700) ? f2b(w[c * 700 + e]) : (short)0;
  }
}

// dw_w [NL][512][7] fp32 -> dwt [NL][7][512] fp32
__global__ __launch_bounds__(256) void k_cvt_dwt(const float* __restrict__ w,
                                                 float* __restrict__ d) {
  const int n = NL_ * 7 * CH_;
  for (int i = blockIdx.x * 256 + threadIdx.x; i < n; i += gridDim.x * 256) {
    int l = i / (7 * CH_), r = i - l * 7 * CH_;
    int k = r >> 9, c = r & 511;
    d[i] = w[((size_t)l * CH_ + c) * 7 + k];
  }
}

// x[b][ci][t] fp32 -> xim[b*T+t][ci*7+k] = x[b,ci,t+k-3] bf16 (0 pad)
__global__ __launch_bounds__(256) void k_im2col(const float* __restrict__ x,
                                                short* __restrict__ xim) {
  const int total = BT * KIN;
  for (int i = blockIdx.x * 256 + threadIdx.x; i < total; i += gridDim.x * 256) {
    int m = i / KIN, e = i - m * KIN;
    int b = m >> 10, t = m & 1023;
    int ci = e / 7, k = e - ci * 7;
    int tt = t + k - 3;
    float v = (e < 700 && tt >= 0 && tt < T_) ? x[((b * CIN + ci) << 10) + tt] : 0.f;
    xim[i] = f2b(v);
  }
}

// zero the 4+4 pad rows of o1p per batch
__global__ __launch_bounds__(256) void k_zeropad(short* __restrict__ o1p) {
  int i = blockIdx.x * 256 + threadIdx.x;  // 131072
  int b = i >> 13;
  int r8 = (i >> 10) & 7;
  int nn = i & 1023;
  int row = r8 < 4 ? r8 : (OROWS - 8 + r8);
  o1p[((size_t)b * OROWS + row) * NFFT_ + nn] = 0;
}

// ---------------- layernorm bf16 -> bf16 (row of 512) -----------------------
__global__ __launch_bounds__(256) void k_lnb(const short* __restrict__ in,
                                             short* __restrict__ outp,
                                             const float* __restrict__ g,
                                             const float* __restrict__ bta) {
  int row = blockIdx.x, tid = threadIdx.x;
  unsigned u = *reinterpret_cast<const unsigned*>(&in[(size_t)row * CH_ + tid * 2]);
  float v0 = __uint_as_float(u << 16);
  float v1 = __uint_as_float(u & 0xffff0000u);
  float s = v0 + v1, q = v0 * v0 + v1 * v1;
#pragma unroll
  for (int o = 32; o > 0; o >>= 1) { s += __shfl_down(s, o); q += __shfl_down(q, o); }
  __shared__ float sh[8];
  int wid = tid >> 6, lane = tid & 63;
  if (lane == 0) { sh[wid] = s; sh[wid + 4] = q; }
  __syncthreads();
  float S = sh[0] + sh[1] + sh[2] + sh[3];
  float Q = sh[4] + sh[5] + sh[6] + sh[7];
  float mu  = S * (1.f / 512.f);
  float var = Q * (1.f / 512.f) - mu * mu;
  float r = rsqrtf(var + 1e-5f);
  float x0 = (v0 - mu) * r * g[tid * 2]     + bta[tid * 2];
  float x1 = (v1 - mu) * r * g[tid * 2 + 1] + bta[tid * 2 + 1];
  unsigned o = ((unsigned)(unsigned short)f2b(x0)) |
               (((unsigned)(unsigned short)f2b(x1)) << 16);
  *reinterpret_cast<unsigned*>(&outp[(size_t)row * CH_ + tid * 2]) = o;
}

// ---------------- fused depthwise 7-tap + LN, bf16, wave-per-row ------------
__global__ __launch_bounds__(256) void k_dwln(const short* __restrict__ h,
                                              const float* __restrict__ dwt,  // [7][512]
                                              const float* __restrict__ dwb,
                                              const float* __restrict__ g,
                                              const float* __restrict__ bta,
                                              short* __restrict__ yb) {
  int b = blockIdx.x, t0 = blockIdx.y * 32;
  int tid = threadIdx.x, lane = tid & 63, w = tid >> 6;
  __shared__ short hs[38][512];
  for (int e = tid; e < 38 * 64; e += 256) {
    int row = e >> 6, seg = (e & 63) << 3;
    int t = t0 - 3 + row;
    s16x8 v = {};
    if (t >= 0 && t < T_)
      v = *reinterpret_cast<const s16x8*>(&h[((size_t)((b << 10) + t)) * CH_ + seg]);
    *reinterpret_cast<s16x8*>(&hs[row][seg]) = v;
  }
  const int c0 = lane << 3;
  float wk[7][8];
#pragma unroll
  for (int k = 0; k < 7; ++k) {
    f32x4 lo = *reinterpret_cast<const f32x4*>(&dwt[k * CH_ + c0]);
    f32x4 hi = *reinterpret_cast<const f32x4*>(&dwt[k * CH_ + c0 + 4]);
#pragma unroll
    for (int j = 0; j < 4; ++j) { wk[k][j] = lo[j]; wk[k][j + 4] = hi[j]; }
  }
  float bb[8], gg[8], be[8];
  {
    f32x4 a = *reinterpret_cast<const f32x4*>(&dwb[c0]);
    f32x4 b4 = *reinterpret_cast<const f32x4*>(&dwb[c0 + 4]);
    f32x4 c = *reinterpret_cast<const f32x4*>(&g[c0]);
    f32x4 d = *reinterpret_cast<const f32x4*>(&g[c0 + 4]);
    f32x4 e = *reinterpret_cast<const f32x4*>(&bta[c0]);
    f32x4 f = *reinterpret_cast<const f32x4*>(&bta[c0 + 4]);
#pragma unroll
    for (int j = 0; j < 4; ++j) {
      bb[j] = a[j]; bb[j + 4] = b4[j];
      gg[j] = c[j]; gg[j + 4] = d[j];
      be[j] = e[j]; be[j + 4] = f[j];
    }
  }
  __syncthreads();
#pragma unroll
  for (int i = 0; i < 8; ++i) {
    int r = w * 8 + i;
    float acc[8];
#pragma unroll
    for (int j = 0; j < 8; ++j) acc[j] = bb[j];
#pragma unroll
    for (int k = 0; k < 7; ++k) {
      s16x8 hv = *reinterpret_cast<const s16x8*>(&hs[r + k][c0]);
#pragma unroll
      for (int j = 0; j < 8; ++j) acc[j] += b2f(hv[j]) * wk[k][j];
    }
    float s = 0.f, q = 0.f;
#pragma unroll
    for (int j = 0; j < 8; ++j) { s += acc[j]; q += acc[j] * acc[j]; }
#pragma unroll
    for (int o = 32; o > 0; o >>= 1) { s += __shfl_xor(s, o); q += __shfl_xor(q, o); }
    float mu  = s * (1.f / 512.f);
    float var = q * (1.f / 512.f) - mu * mu;
    float rr = rsqrtf(var + 1e-5f);
    s16x8 ov;
#pragma unroll
    for (int j = 0; j < 8; ++j) ov[j] = f2b((acc[j] - mu) * rr * gg[j] + be[j]);
    *reinterpret_cast<s16x8*>(&yb[((size_t)((b << 10) + t0 + r)) * CH_ + c0]) = ov;
  }
}

// ---------------- bf16 MFMA GEMM: C[m,n] = sum_k A[m,k]*Bw[n,k] -------------
// 128x128 tile, BK=64, 4 waves, 4x4 frags of 16x16x32. M fixed 16384.
// XCD-grouped mapping: the ny n-tiles of one m-tile are consecutive ids on
// one XCD (id%8 == m-tile%8) -> A-panel fetched once per XCD.
// MODE 0: obf = bf16(acc+bias)
// MODE 1: obf = bf16(gelu(acc+bias))
// MODE 2: obf[m][n] = bf16(obf + (acc+bias)*scale)   (residual RMW)
// MODE 3: obf = bf16(acc+bias) at padded o1 rows (b*OROWS+4+t)
template <int MODE>
__global__ __launch_bounds__(256) void k_mgemm(const short* __restrict__ A,
                                               const short* __restrict__ Bw,
                                               const float* __restrict__ bias,
                                               const float* __restrict__ scale,
                                               short* __restrict__ obf,
                                               int N, int K) {
  __shared__ __align__(16) short As[128 * 64];
  __shared__ __align__(16) short Bs[128 * 64];
  const int tid = threadIdx.x;
  const int lane = tid & 63, w = tid >> 6;
  const int id = blockIdx.x;
  const int ny = N >> 7;
  const int g8 = id >> 3;
  const int gq = g8 / ny;
  const int mt = (id & 7) + (gq << 3);
  const int nt = g8 - gq * ny;
  const int m0 = mt << 7, n0 = nt << 7;
  const int wr = (w >> 1) * 64, wc = (w & 1) * 64;
  f32x4 acc[4][4];
#pragma unroll
  for (int i = 0; i < 4; ++i)
#pragma unroll
    for (int j = 0; j < 4; ++j) acc[i][j] = (f32x4){0.f, 0.f, 0.f, 0.f};

  const short* Ab = A + (size_t)m0 * K;
  const short* Bb = Bw + (size_t)n0 * K;
  int r_[4], kk_[4];
#pragma unroll
  for (int j = 0; j < 4; ++j) {
    int c = tid + j * 256;
    r_[j] = c >> 3;
    kk_[j] = (((c & 7) ^ (r_[j] & 7)) * 8);   // inverse-swizzled source (rule #21)
  }
  short* AsB[4]; short* BsB[4];
#pragma unroll
  for (int j = 0; j < 4; ++j) {
    AsB[j] = As + (j * 256 + w * 64) * 8;
    BsB[j] = Bs + (j * 256 + w * 64) * 8;
  }
  const int ar = wr + (lane & 15);
  const int br = wc + (lane & 15);
  const int hi = lane >> 4;

  for (int k0 = 0; k0 < K; k0 += 64) {
#pragma unroll
    for (int j = 0; j < 4; ++j) gl2lds16(Ab + (size_t)r_[j] * K + k0 + kk_[j], AsB[j]);
#pragma unroll
    for (int j = 0; j < 4; ++j) gl2lds16(Bb + (size_t)r_[j] * K + k0 + kk_[j], BsB[j]);
    asm volatile("s_waitcnt vmcnt(0)" ::: "memory");
    __syncthreads();
#pragma unroll
    for (int ks = 0; ks < 2; ++ks) {
      bf16x8 a[4], b[4];
#pragma unroll
      for (int f = 0; f < 4; ++f) {
        int row = ar + f * 16;
        a[f] = *reinterpret_cast<const bf16x8*>(&As[row * 64 + (((ks * 4 + hi) ^ (row & 7)) * 8)]);
      }
#pragma unroll
      for (int f = 0; f < 4; ++f) {
        int row = br + f * 16;
        b[f] = *reinterpret_cast<const bf16x8*>(&Bs[row * 64 + (((ks * 4 + hi) ^ (row & 7)) * 8)]);
      }
#pragma unroll
      for (int fi = 0; fi < 4; ++fi)
#pragma unroll
        for (int fj = 0; fj < 4; ++fj)
          acc[fi][fj] = __builtin_amdgcn_mfma_f32_16x16x32_bf16(a[fi], b[fj], acc[fi][fj], 0, 0, 0);
    }
    __syncthreads();
  }
  // epilogue: D row = (lane>>4)*4 + reg, col = lane&15
  const int mb = m0 + wr + (hi << 2);
  const int nb = n0 + wc + (lane & 15);
#pragma unroll
  for (int fj = 0; fj < 4; ++fj) {
    int n = nb + fj * 16;
    float bi = bias[n];
    float sc = (MODE == 2) ? scale[n] : 0.f;
#pragma unroll
    for (int fi = 0; fi < 4; ++fi) {
      int mrow = mb + fi * 16;
#pragma unroll
      for (int r = 0; r < 4; ++r) {
        float v = acc[fi][fj][r] + bi;
        int m = mrow + r;
        if (MODE == 0) {
          obf[(size_t)m * N + n] = f2b(v);
        } else if (MODE == 1) {
          v = 0.5f * v * (1.f + erff(v * 0.70710678118654752440f));
          obf[(size_t)m * N + n] = f2b(v);
        } else if (MODE == 2) {
          size_t idx = (size_t)m * N + n;
          obf[idx] = f2b(b2f(obf[idx]) + v * sc);
        } else {
          int bb = m >> 10, t = m & 1023;
          obf[((size_t)(bb * OROWS + 4 + t)) * NFFT_ + n] = f2b(v);
        }
      }
    }
  }
}

// ---------------- overlap conv as 4 shift-accumulated MFMA GEMMs ------------
// o2[b][l][c] = sum_{k=0..3} sum_n o1p[b][l+1+k][n] * ovb[k][c][n]
__global__ __launch_bounds__(256) void k_ovgemm(const short* __restrict__ o1p,
                                                const short* __restrict__ ovb,
                                                float* __restrict__ o2) {
  __shared__ __align__(16) short As[128 * 64];
  __shared__ __align__(16) short Bs[128 * 64];
  const int tid = threadIdx.x;
  const int lane = tid & 63, w = tid >> 6;
  const int l0 = blockIdx.x * 128, c0 = blockIdx.y * 128, b = blockIdx.z;
  const int wr = (w >> 1) * 64, wc = (w & 1) * 64;
  f32x4 acc[4][4];
#pragma unroll
  for (int i = 0; i < 4; ++i)
#pragma unroll
    for (int j = 0; j < 4; ++j) acc[i][j] = (f32x4){0.f, 0.f, 0.f, 0.f};

  const short* Ab = o1p + (size_t)b * OROWS * NFFT_;
  int r_[4], kk_[4];
#pragma unroll
  for (int j = 0; j < 4; ++j) {
    int c = tid + j * 256;
    r_[j] = c >> 3;
    kk_[j] = (((c & 7) ^ (r_[j] & 7)) * 8);
  }
  short* AsB[4]; short* BsB[4];
#pragma unroll
  for (int j = 0; j < 4; ++j) {
    AsB[j] = As + (j * 256 + w * 64) * 8;
    BsB[j] = Bs + (j * 256 + w * 64) * 8;
  }
  const int ar = wr + (lane & 15);
  const int br = wc + (lane & 15);
  const int hi = lane >> 4;

  for (int ksh = 0; ksh < 4; ++ksh) {
    const short* Bb = ovb + ((size_t)(ksh * HOP_ + c0)) * NFFT_;
    for (int k0 = 0; k0 < NFFT_; k0 += 64) {
#pragma unroll
      for (int j = 0; j < 4; ++j) {
        int tp = l0 + r_[j] + 1 + ksh;
        tp = tp > (OROWS - 1) ? (OROWS - 1) : tp;   // clamp into zero pad
        gl2lds16(Ab + (size_t)tp * NFFT_ + k0 + kk_[j], AsB[j]);
      }
#pragma unroll
      for (int j = 0; j < 4; ++j) gl2lds16(Bb + (size_t)r_[j] * NFFT_ + k0 + kk_[j], BsB[j]);
      asm volatile("s_waitcnt vmcnt(0)" ::: "memory");
      __syncthreads();
#pragma unroll
      for (int ks = 0; ks < 2; ++ks) {
        bf16x8 a[4], bfr[4];
#pragma unroll
        for (int f = 0; f < 4; ++f) {
          int row = ar + f * 16;
          a[f] = *reinterpret_cast<const bf16x8*>(&As[row * 64 + (((ks * 4 + hi) ^ (row & 7)) * 8)]);
        }
#pragma unroll
        for (int f = 0; f < 4; ++f) {
          int row = br + f * 16;
          bfr[f] = *reinterpret_cast<const bf16x8*>(&Bs[row * 64 + (((ks * 4 + hi) ^ (row & 7)) * 8)]);
        }
#pragma unroll
        for (int fi = 0; fi < 4; ++fi)
#pragma unroll
          for (int fj = 0; fj < 4; ++fj)
            acc[fi][fj] = __builtin_amdgcn_mfma_f32_16x16x32_bf16(a[fi], bfr[fj], acc[fi][fj], 0, 0, 0);
      }
      __syncthreads();
    }
  }
  const int lb = l0 + wr + (hi << 2);
  const int cb = c0 + wc + (lane & 15);
#pragma unroll
  for (int fj = 0; fj < 4; ++fj) {
    int c = cb + fj * 16;
#pragma unroll
    for (int fi = 0; fi < 4; ++fi) {
#pragma unroll
      for (int r = 0; r < 4; ++r) {
        int l = lb + fi * 16 + r;
        if (l < L_) o2[((size_t)b * L_ + l) * HOP_ + c] = acc[fi][fj][r];
      }
    }
  }
}

// ---------------- final gather-sum over o2[b][l][c] -------------------------
__global__ __launch_bounds__(256) void k_oadd(const float* __restrict__ o2,
                                              float* __restrict__ out) {
  int b = blockIdx.x;
  int t = blockIdx.y * 256 + threadIdx.x;
  int m = t + 2;
  float s = 0.f;
  for (int c = 0; c < HOP_; ++c) {
    s += o2[((size_t)b * L_ + m) * HOP_ + c];
    m -= 4;
    if (m < 0) m += L_;
  }
  out[b * T_ + t] = s;
}

extern "C" void kernel_launch(void* const* d_in, const int* in_sizes, int n_in,
                              void* d_out, int out_size, void* d_ws, size_t ws_size,
                              hipStream_t stream) {
  const float* x      = (const float*)d_in[0];
  const float* in_w   = (const float*)d_in[1];
  const float* in_b   = (const float*)d_in[2];
  const float* norm_g = (const float*)d_in[3];
  const float* norm_b = (const float*)d_in[4];
  const float* dw_w   = (const float*)d_in[5];
  const float* dw_b   = (const float*)d_in[6];
  const float* ln_g   = (const float*)d_in[7];
  const float* ln_b   = (const float*)d_in[8];
  const float* pw1_w  = (const float*)d_in[9];
  const float* pw1_b  = (const float*)d_in[10];
  const float* pw2_w  = (const float*)d_in[11];
  const float* pw2_b  = (const float*)d_in[12];
  const float* ls     = (const float*)d_in[13];
  const float* normLg = (const float*)d_in[14];
  const float* normLb = (const float*)d_in[15];
  const float* out_w  = (const float*)d_in[16];
  const float* out_b  = (const float*)d_in[17];
  const float* ov_w   = (const float*)d_in[18];
  float* out = (float*)d_out;

  char* p = (char*)d_ws;
  short* hb   = (short*)p; p += (size_t)BT * CH_ * 2;        // 16.78 MB
  short* yb   = (short*)p; p += (size_t)BT * CH_ * 2;        // 16.78 MB
  short* zb   = (short*)p; p += (size_t)BT * HCH_ * 2;       // 50.33 MB
  short* pw1b = (short*)p; p += (size_t)NL_ * HCH_ * CH_ * 2;
  short* pw2b = (short*)p; p += (size_t)NL_ * CH_ * HCH_ * 2;
  short* owb  = (short*)p; p += (size_t)NFFT_ * CH_ * 2;
  short* ovb  = (short*)p; p += (size_t)4 * HOP_ * NFFT_ * 2;
  float* dwt  = (float*)p; p += (size_t)NL_ * 7 * CH_ * 4;
  short* xim  = zb;                        // alias: zb not yet used
  short* wib  = zb + (size_t)BT * KIN;     // fits (23.6 MB < 50.3 MB)
  short* hbL  = yb;                        // alias: yb dead when final LN runs
  short* o1p  = zb;                        // alias: zb dead after layer loop
  float* o2   = (float*)hb;                // spans hb + first 64KB of yb; both
                                           // dead once ovgemm runs

  k_cvt<<<4096, 256, 0, stream>>>(pw1_w, pw1b, NL_ * HCH_ * CH_);
  k_cvt<<<4096, 256, 0, stream>>>(pw2_w, pw2b, NL_ * CH_ * HCH_);
  k_cvt<<<2048, 256, 0, stream>>>(out_w, owb, NFFT_ * CH_);
  k_cvt_ov<<<4096, 256, 0, stream>>>(ov_w, ovb);
  k_cvt_inw<<<1408, 256, 0, stream>>>(in_w, wib);
  k_cvt_dwt<<<112, 256, 0, stream>>>(dw_w, dwt);
  k_im2col<<<8192, 256, 0, stream>>>(x, xim);

  k_mgemm<0><<<512, 256, 0, stream>>>(xim, wib, in_b, nullptr, hb, CH_, KIN);
  k_lnb<<<BT, 256, 0, stream>>>(hb, hb, norm_g, norm_b);
  for (int l = 0; l < NL_; ++l) {
    k_dwln<<<dim3(B_, T_ / 32), 256, 0, stream>>>(
        hb, dwt + (size_t)l * 7 * CH_, dw_b + l * CH_,
        ln_g + l * CH_, ln_b + l * CH_, yb);
    k_mgemm<1><<<1536, 256, 0, stream>>>(
        yb, pw1b + (size_t)l * HCH_ * CH_, pw1_b + l * HCH_, nullptr, zb,
        HCH_, CH_);
    k_mgemm<2><<<512, 256, 0, stream>>>(
        zb, pw2b + (size_t)l * CH_ * HCH_, pw2_b + l * CH_, ls + l * CH_, hb,
        CH_, HCH_);
  }
  k_lnb<<<BT, 256, 0, stream>>>(hb, hbL, normLg, normLb);
  k_mgemm<3><<<1024, 256, 0, stream>>>(hbL, owb, out_b, nullptr, o1p, NFFT_, CH_);
  k_zeropad<<<512, 256, 0, stream>>>(o1p);
  k_ovgemm<<<dim3(9, 2, 16), 256, 0, stream>>>(o1p, ovb, o2);
  k_oadd<<<dim3(B_, 4), 256, 0, stream>>>(o2, out);
}

// Round 5
// 978.469 us; speedup vs baseline: 7.6810x; 1.0672x over previous
//
#include <hip/hip_runtime.h>

#define B_    16
#define CIN   100
#define T_    1024
#define CH_   512
#define HCH_  1536
#define NL_   8
#define NFFT_ 1024
#define HOP_  256
#define BT    (B_ * T_)
#define L_    1027
#define OROWS 1032   // padded o1 rows per batch: [4 zero | 1024 data | 4 zero]
#define KIN   704    // im2col K for in-conv (100*7 -> pad 704)

typedef __bf16 bf16x8 __attribute__((ext_vector_type(8)));
typedef float f32x4 __attribute__((ext_vector_type(4)));
typedef short s16x8 __attribute__((ext_vector_type(8)));

__device__ __forceinline__ short f2b(float f) {
  unsigned u = __float_as_uint(f);
  u += 0x7fffu + ((u >> 16) & 1u);
  return (short)(u >> 16);
}
__device__ __forceinline__ float b2f(short s) {
  return __uint_as_float(((unsigned)(unsigned short)s) << 16);
}

__device__ __forceinline__ void gl2lds16(const void* g, void* l) {
  __builtin_amdgcn_global_load_lds(
      (__attribute__((address_space(1))) void*)g,
      (__attribute__((address_space(3))) void*)l, 16, 0, 0);
}

// ---------------- weight fp32 -> bf16 (contiguous) --------------------------
__global__ __launch_bounds__(256) void k_cvt(const float* __restrict__ s,
                                             short* __restrict__ d, int n) {
  for (int i = blockIdx.x * 256 + threadIdx.x; i < n; i += gridDim.x * 256)
    d[i] = f2b(s[i]);
}

// ov_w[c][n][k] -> ovb[k][c][n] bf16
__global__ __launch_bounds__(256) void k_cvt_ov(const float* __restrict__ w,
                                                short* __restrict__ d) {
  const int n = 4 * HOP_ * NFFT_;
  for (int i = blockIdx.x * 256 + threadIdx.x; i < n; i += gridDim.x * 256) {
    int k = i >> 18;
    int rem = i & 0x3FFFF;
    int c = rem >> 10, nn = rem & 1023;
    d[i] = f2b(w[((size_t)c * NFFT_ + nn) * 4 + k]);
  }
}

// in_w[c][ci][k] (700 contiguous per c) -> wib[c][704] bf16, pad 0
__global__ __launch_bounds__(256) void k_cvt_inw(const float* __restrict__ w,
                                                 short* __restrict__ d) {
  const int n = CH_ * KIN;
  for (int i = blockIdx.x * 256 + threadIdx.x; i < n; i += gridDim.x * 256) {
    int c = i / KIN, e = i - c * KIN;
    d[i] = (e < 700) ? f2b(w[c * 700 + e]) : (short)0;
  }
}

// dw_w [NL][512][7] fp32 -> dwt [NL][7][512] fp32
__global__ __launch_bounds__(256) void k_cvt_dwt(const float* __restrict__ w,
                                                 float* __restrict__ d) {
  const int n = NL_ * 7 * CH_;
  for (int i = blockIdx.x * 256 + threadIdx.x; i < n; i += gridDim.x * 256) {
    int l = i / (7 * CH_), r = i - l * 7 * CH_;
    int k = r >> 9, c = r & 511;
    d[i] = w[((size_t)l * CH_ + c) * 7 + k];
  }
}

// x[b][ci][t] fp32 -> xim[b*T+t][ci*7+k] = x[b,ci,t+k-3] bf16 (0 pad)
__global__ __launch_bounds__(256) void k_im2col(const float* __restrict__ x,
                                                short* __restrict__ xim) {
  const int total = BT * KIN;
  for (int i = blockIdx.x * 256 + threadIdx.x; i < total; i += gridDim.x * 256) {
    int m = i / KIN, e = i - m * KIN;
    int b = m >> 10, t = m & 1023;
    int ci = e / 7, k = e - ci * 7;
    int tt = t + k - 3;
    float v = (e < 700 && tt >= 0 && tt < T_) ? x[((b * CIN + ci) << 10) + tt] : 0.f;
    xim[i] = f2b(v);
  }
}

// zero the 4+4 pad rows of o1p per batch
__global__ __launch_bounds__(256) void k_zeropad(short* __restrict__ o1p) {
  int i = blockIdx.x * 256 + threadIdx.x;  // 131072
  int b = i >> 13;
  int r8 = (i >> 10) & 7;
  int nn = i & 1023;
  int row = r8 < 4 ? r8 : (OROWS - 8 + r8);
  o1p[((size_t)b * OROWS + row) * NFFT_ + nn] = 0;
}

// ---------------- layernorm bf16 -> bf16 (row of 512) -----------------------
__global__ __launch_bounds__(256) void k_lnb(const short* __restrict__ in,
                                             short* __restrict__ outp,
                                             const float* __restrict__ g,
                                             const float* __restrict__ bta) {
  int row = blockIdx.x, tid = threadIdx.x;
  unsigned u = *reinterpret_cast<const unsigned*>(&in[(size_t)row * CH_ + tid * 2]);
  float v0 = __uint_as_float(u << 16);
  float v1 = __uint_as_float(u & 0xffff0000u);
  float s = v0 + v1, q = v0 * v0 + v1 * v1;
#pragma unroll
  for (int o = 32; o > 0; o >>= 1) { s += __shfl_down(s, o); q += __shfl_down(q, o); }
  __shared__ float sh[8];
  int wid = tid >> 6, lane = tid & 63;
  if (lane == 0) { sh[wid] = s; sh[wid + 4] = q; }
  __syncthreads();
  float S = sh[0] + sh[1] + sh[2] + sh[3];
  float Q = sh[4] + sh[5] + sh[6] + sh[7];
  float mu  = S * (1.f / 512.f);
  float var = Q * (1.f / 512.f) - mu * mu;
  float r = rsqrtf(var + 1e-5f);
  float x0 = (v0 - mu) * r * g[tid * 2]     + bta[tid * 2];
  float x1 = (v1 - mu) * r * g[tid * 2 + 1] + bta[tid * 2 + 1];
  unsigned o = ((unsigned)(unsigned short)f2b(x0)) |
               (((unsigned)(unsigned short)f2b(x1)) << 16);
  *reinterpret_cast<unsigned*>(&outp[(size_t)row * CH_ + tid * 2]) = o;
}

// ---------------- fused depthwise 7-tap + LN, bf16, wave-per-row ------------
__global__ __launch_bounds__(256) void k_dwln(const short* __restrict__ h,
                                              const float* __restrict__ dwt,  // [7][512]
                                              const float* __restrict__ dwb,
                                              const float* __restrict__ g,
                                              const float* __restrict__ bta,
                                              short* __restrict__ yb) {
  int b = blockIdx.x, t0 = blockIdx.y * 32;
  int tid = threadIdx.x, lane = tid & 63, w = tid >> 6;
  __shared__ short hs[38][512];
  for (int e = tid; e < 38 * 64; e += 256) {
    int row = e >> 6, seg = (e & 63) << 3;
    int t = t0 - 3 + row;
    s16x8 v = {};
    if (t >= 0 && t < T_)
      v = *reinterpret_cast<const s16x8*>(&h[((size_t)((b << 10) + t)) * CH_ + seg]);
    *reinterpret_cast<s16x8*>(&hs[row][seg]) = v;
  }
  const int c0 = lane << 3;
  float wk[7][8];
#pragma unroll
  for (int k = 0; k < 7; ++k) {
    f32x4 lo = *reinterpret_cast<const f32x4*>(&dwt[k * CH_ + c0]);
    f32x4 hi = *reinterpret_cast<const f32x4*>(&dwt[k * CH_ + c0 + 4]);
#pragma unroll
    for (int j = 0; j < 4; ++j) { wk[k][j] = lo[j]; wk[k][j + 4] = hi[j]; }
  }
  float bb[8], gg[8], be[8];
  {
    f32x4 a = *reinterpret_cast<const f32x4*>(&dwb[c0]);
    f32x4 b4 = *reinterpret_cast<const f32x4*>(&dwb[c0 + 4]);
    f32x4 c = *reinterpret_cast<const f32x4*>(&g[c0]);
    f32x4 d = *reinterpret_cast<const f32x4*>(&g[c0 + 4]);
    f32x4 e = *reinterpret_cast<const f32x4*>(&bta[c0]);
    f32x4 f = *reinterpret_cast<const f32x4*>(&bta[c0 + 4]);
#pragma unroll
    for (int j = 0; j < 4; ++j) {
      bb[j] = a[j]; bb[j + 4] = b4[j];
      gg[j] = c[j]; gg[j + 4] = d[j];
      be[j] = e[j]; be[j + 4] = f[j];
    }
  }
  __syncthreads();
#pragma unroll
  for (int i = 0; i < 8; ++i) {
    int r = w * 8 + i;
    float acc[8];
#pragma unroll
    for (int j = 0; j < 8; ++j) acc[j] = bb[j];
#pragma unroll
    for (int k = 0; k < 7; ++k) {
      s16x8 hv = *reinterpret_cast<const s16x8*>(&hs[r + k][c0]);
#pragma unroll
      for (int j = 0; j < 8; ++j) acc[j] += b2f(hv[j]) * wk[k][j];
    }
    float s = 0.f, q = 0.f;
#pragma unroll
    for (int j = 0; j < 8; ++j) { s += acc[j]; q += acc[j] * acc[j]; }
#pragma unroll
    for (int o = 32; o > 0; o >>= 1) { s += __shfl_xor(s, o); q += __shfl_xor(q, o); }
    float mu  = s * (1.f / 512.f);
    float var = q * (1.f / 512.f) - mu * mu;
    float rr = rsqrtf(var + 1e-5f);
    s16x8 ov;
#pragma unroll
    for (int j = 0; j < 8; ++j) ov[j] = f2b((acc[j] - mu) * rr * gg[j] + be[j]);
    *reinterpret_cast<s16x8*>(&yb[((size_t)((b << 10) + t0 + r)) * CH_ + c0]) = ov;
  }
}

// ---------------- bf16 MFMA GEMM: C[m,n] = sum_k A[m,k]*Bw[n,k] -------------
// 128x128 tile, BK=64, 4 waves, 4x4 frags of 16x16x32. M fixed 16384.
// XCD-grouped mapping; LDS-staged coalesced epilogue (16B stores).
// MODE 0: obf = bf16(acc+bias)
// MODE 1: obf = bf16(gelu(acc+bias))
// MODE 2: obf[m][n] = bf16(obf + bf16((acc+bias)*scale))   (residual RMW)
// MODE 3: obf = bf16(acc+bias) at padded o1 rows (b*OROWS+4+t)
template <int MODE>
__global__ __launch_bounds__(256) void k_mgemm(const short* __restrict__ A,
                                               const short* __restrict__ Bw,
                                               const float* __restrict__ bias,
                                               const float* __restrict__ scale,
                                               short* __restrict__ obf,
                                               int N, int K) {
  __shared__ __align__(16) short smem[2 * 128 * 64];   // As | Bs, reused as C
  short* As = smem;
  short* Bs = smem + 128 * 64;
  const int tid = threadIdx.x;
  const int lane = tid & 63, w = tid >> 6;
  const int id = blockIdx.x;
  const int ny = N >> 7;
  const int g8 = id >> 3;
  const int gq = g8 / ny;
  const int mt = (id & 7) + (gq << 3);
  const int nt = g8 - gq * ny;
  const int m0 = mt << 7, n0 = nt << 7;
  const int wr = (w >> 1) * 64, wc = (w & 1) * 64;
  f32x4 acc[4][4];
#pragma unroll
  for (int i = 0; i < 4; ++i)
#pragma unroll
    for (int j = 0; j < 4; ++j) acc[i][j] = (f32x4){0.f, 0.f, 0.f, 0.f};

  const short* Ab = A + (size_t)m0 * K;
  const short* Bb = Bw + (size_t)n0 * K;
  int r_[4], kk_[4];
#pragma unroll
  for (int j = 0; j < 4; ++j) {
    int c = tid + j * 256;
    r_[j] = c >> 3;
    kk_[j] = (((c & 7) ^ (r_[j] & 7)) * 8);   // inverse-swizzled source (rule #21)
  }
  short* AsB[4]; short* BsB[4];
#pragma unroll
  for (int j = 0; j < 4; ++j) {
    AsB[j] = As + (j * 256 + w * 64) * 8;
    BsB[j] = Bs + (j * 256 + w * 64) * 8;
  }
  const int ar = wr + (lane & 15);
  const int br = wc + (lane & 15);
  const int hi = lane >> 4;

  for (int k0 = 0; k0 < K; k0 += 64) {
#pragma unroll
    for (int j = 0; j < 4; ++j) gl2lds16(Ab + (size_t)r_[j] * K + k0 + kk_[j], AsB[j]);
#pragma unroll
    for (int j = 0; j < 4; ++j) gl2lds16(Bb + (size_t)r_[j] * K + k0 + kk_[j], BsB[j]);
    asm volatile("s_waitcnt vmcnt(0)" ::: "memory");
    __syncthreads();
#pragma unroll
    for (int ks = 0; ks < 2; ++ks) {
      bf16x8 a[4], b[4];
#pragma unroll
      for (int f = 0; f < 4; ++f) {
        int row = ar + f * 16;
        a[f] = *reinterpret_cast<const bf16x8*>(&As[row * 64 + (((ks * 4 + hi) ^ (row & 7)) * 8)]);
      }
#pragma unroll
      for (int f = 0; f < 4; ++f) {
        int row = br + f * 16;
        b[f] = *reinterpret_cast<const bf16x8*>(&Bs[row * 64 + (((ks * 4 + hi) ^ (row & 7)) * 8)]);
      }
#pragma unroll
      for (int fi = 0; fi < 4; ++fi)
#pragma unroll
        for (int fj = 0; fj < 4; ++fj)
          acc[fi][fj] = __builtin_amdgcn_mfma_f32_16x16x32_bf16(a[fi], b[fj], acc[fi][fj], 0, 0, 0);
    }
    __syncthreads();
  }
  // ---- epilogue: acc -> LDS (bank-conflict-free) -> coalesced 16B stores ----
  short* Cl = smem;                       // 128x128 shorts = 32KB (reuse As+Bs)
  const int colbase = wc + (lane & 15);
#pragma unroll
  for (int fj = 0; fj < 4; ++fj) {
    int cl = colbase + fj * 16;
    int n = n0 + cl;
    float bi = bias[n];
    float sc = (MODE == 2) ? scale[n] : 0.f;
#pragma unroll
    for (int fi = 0; fi < 4; ++fi) {
#pragma unroll
      for (int r = 0; r < 4; ++r) {
        int rl = wr + (hi << 2) + fi * 16 + r;
        float v = acc[fi][fj][r] + bi;
        if (MODE == 1) v = 0.5f * v * (1.f + erff(v * 0.70710678118654752440f));
        if (MODE == 2) v *= sc;
        Cl[rl * 128 + (cl ^ (((rl >> 2) & 3) << 4))] = f2b(v);
      }
    }
  }
  __syncthreads();
  const int cs = (lane & 15) * 8;
#pragma unroll
  for (int it = 0; it < 8; ++it) {
    int rl = w * 32 + it * 4 + (lane >> 4);
    s16x8 v = *reinterpret_cast<const s16x8*>(&Cl[rl * 128 + (cs ^ (((rl >> 2) & 3) << 4))]);
    int m = m0 + rl;
    if (MODE == 2) {
      size_t idx = (size_t)m * N + n0 + cs;
      s16x8 hv = *reinterpret_cast<const s16x8*>(&obf[idx]);
      s16x8 o;
#pragma unroll
      for (int j = 0; j < 8; ++j) o[j] = f2b(b2f(hv[j]) + b2f(v[j]));
      *reinterpret_cast<s16x8*>(&obf[idx]) = o;
    } else if (MODE == 3) {
      int bb = m >> 10, t = m & 1023;
      *reinterpret_cast<s16x8*>(&obf[((size_t)(bb * OROWS + 4 + t)) * NFFT_ + n0 + cs]) = v;
    } else {
      *reinterpret_cast<s16x8*>(&obf[(size_t)m * N + n0 + cs]) = v;
    }
  }
}

// ---------------- overlap conv: A staged once, 4 shifted B-GEMMs ------------
// o2[b][l][c] = sum_{k=0..3} sum_n o1p[b][l+1+k][n] * ovb[k][c][n]
__global__ __launch_bounds__(256) void k_ovgemm(const short* __restrict__ o1p,
                                                const short* __restrict__ ovb,
                                                float* __restrict__ o2) {
  __shared__ __align__(16) short As[136 * 64];   // rows l0+1 .. l0+136
  __shared__ __align__(16) short Bs[128 * 64];
  const int tid = threadIdx.x;
  const int lane = tid & 63, w = tid >> 6;
  const int l0 = blockIdx.x * 128, c0 = blockIdx.y * 128, b = blockIdx.z;
  const int wr = (w >> 1) * 64, wc = (w & 1) * 64;
  f32x4 acc[4][4];
#pragma unroll
  for (int i = 0; i < 4; ++i)
#pragma unroll
    for (int j = 0; j < 4; ++j) acc[i][j] = (f32x4){0.f, 0.f, 0.f, 0.f};

  const short* Ab = o1p + (size_t)b * OROWS * NFFT_;
  const int ar = wr + (lane & 15);
  const int br = wc + (lane & 15);
  const int hi = lane >> 4;
  // per-lane staging geometry
  const int sl_row = lane >> 3;            // 0..7 within a 8-row chunk
  const int sl_j   = lane & 7;             // 16B chunk within row

  for (int k0 = 0; k0 < NFFT_; k0 += 64) {
    // stage A: 17 chunks of 8 rows x 128B (rows shared across all 4 shifts)
    for (int c = w; c < 17; c += 4) {
      int lr = c * 8 + sl_row;
      int gr = l0 + 1 + lr;
      if (gr > OROWS - 1) gr = OROWS - 1;
      int j = sl_j ^ (lr & 7);
      gl2lds16(Ab + (size_t)gr * NFFT_ + k0 + j * 8, As + c * 512);
    }
#pragma unroll
    for (int ksh = 0; ksh < 4; ++ksh) {
      const short* Bb = ovb + ((size_t)(ksh * HOP_ + c0)) * NFFT_;
#pragma unroll
      for (int c = 0; c < 4; ++c) {
        int ch = w * 4 + c;
        int lr = ch * 8 + sl_row;
        int j = sl_j ^ (lr & 7);
        gl2lds16(Bb + (size_t)lr * NFFT_ + k0 + j * 8, Bs + ch * 512);
      }
      asm volatile("s_waitcnt vmcnt(0)" ::: "memory");
      __syncthreads();
#pragma unroll
      for (int ks = 0; ks < 2; ++ks) {
        bf16x8 a[4], bfr[4];
#pragma unroll
        for (int f = 0; f < 4; ++f) {
          int row = ar + f * 16 + ksh;     // shifted A row
          a[f] = *reinterpret_cast<const bf16x8*>(&As[row * 64 + (((ks * 4 + hi) ^ (row & 7)) * 8)]);
        }
#pragma unroll
        for (int f = 0; f < 4; ++f) {
          int row = br + f * 16;
          bfr[f] = *reinterpret_cast<const bf16x8*>(&Bs[row * 64 + (((ks * 4 + hi) ^ (row & 7)) * 8)]);
        }
#pragma unroll
        for (int fi = 0; fi < 4; ++fi)
#pragma unroll
          for (int fj = 0; fj < 4; ++fj)
            acc[fi][fj] = __builtin_amdgcn_mfma_f32_16x16x32_bf16(a[fi], bfr[fj], acc[fi][fj], 0, 0, 0);
      }
      __syncthreads();
    }
  }
  const int lb = l0 + wr + (hi << 2);
  const int cb = c0 + wc + (lane & 15);
#pragma unroll
  for (int fj = 0; fj < 4; ++fj) {
    int c = cb + fj * 16;
#pragma unroll
    for (int fi = 0; fi < 4; ++fi) {
#pragma unroll
      for (int r = 0; r < 4; ++r) {
        int l = lb + fi * 16 + r;
        if (l < L_) o2[((size_t)b * L_ + l) * HOP_ + c] = acc[fi][fj][r];
      }
    }
  }
}

// ---------------- final gather-sum over o2[b][l][c] -------------------------
__global__ __launch_bounds__(256) void k_oadd(const float* __restrict__ o2,
                                              float* __restrict__ out) {
  int b = blockIdx.x;
  int t = blockIdx.y * 256 + threadIdx.x;
  int m = t + 2;
  float s = 0.f;
  for (int c = 0; c < HOP_; ++c) {
    s += o2[((size_t)b * L_ + m) * HOP_ + c];
    m -= 4;
    if (m < 0) m += L_;
  }
  out[b * T_ + t] = s;
}

extern "C" void kernel_launch(void* const* d_in, const int* in_sizes, int n_in,
                              void* d_out, int out_size, void* d_ws, size_t ws_size,
                              hipStream_t stream) {
  const float* x      = (const float*)d_in[0];
  const float* in_w   = (const float*)d_in[1];
  const float* in_b   = (const float*)d_in[2];
  const float* norm_g = (const float*)d_in[3];
  const float* norm_b = (const float*)d_in[4];
  const float* dw_w   = (const float*)d_in[5];
  const float* dw_b   = (const float*)d_in[6];
  const float* ln_g   = (const float*)d_in[7];
  const float* ln_b   = (const float*)d_in[8];
  const float* pw1_w  = (const float*)d_in[9];
  const float* pw1_b  = (const float*)d_in[10];
  const float* pw2_w  = (const float*)d_in[11];
  const float* pw2_b  = (const float*)d_in[12];
  const float* ls     = (const float*)d_in[13];
  const float* normLg = (const float*)d_in[14];
  const float* normLb = (const float*)d_in[15];
  const float* out_w  = (const float*)d_in[16];
  const float* out_b  = (const float*)d_in[17];
  const float* ov_w   = (const float*)d_in[18];
  float* out = (float*)d_out;

  char* p = (char*)d_ws;
  short* hb   = (short*)p; p += (size_t)BT * CH_ * 2;        // 16.78 MB
  short* yb   = (short*)p; p += (size_t)BT * CH_ * 2;        // 16.78 MB
  short* zb   = (short*)p; p += (size_t)BT * HCH_ * 2;       // 50.33 MB
  short* pw1b = (short*)p; p += (size_t)NL_ * HCH_ * CH_ * 2;
  short* pw2b = (short*)p; p += (size_t)NL_ * CH_ * HCH_ * 2;
  short* owb  = (short*)p; p += (size_t)NFFT_ * CH_ * 2;
  short* ovb  = (short*)p; p += (size_t)4 * HOP_ * NFFT_ * 2;
  float* dwt  = (float*)p; p += (size_t)NL_ * 7 * CH_ * 4;
  short* xim  = zb;                        // alias: zb not yet used
  short* wib  = zb + (size_t)BT * KIN;     // fits (23.6 MB < 50.3 MB)
  short* hbL  = yb;                        // alias: yb dead when final LN runs
  short* o1p  = zb;                        // alias: zb dead after layer loop
  float* o2   = (float*)hb;                // spans hb + start of yb; both dead

  k_cvt<<<4096, 256, 0, stream>>>(pw1_w, pw1b, NL_ * HCH_ * CH_);
  k_cvt<<<4096, 256, 0, stream>>>(pw2_w, pw2b, NL_ * CH_ * HCH_);
  k_cvt<<<2048, 256, 0, stream>>>(out_w, owb, NFFT_ * CH_);
  k_cvt_ov<<<4096, 256, 0, stream>>>(ov_w, ovb);
  k_cvt_inw<<<1408, 256, 0, stream>>>(in_w, wib);
  k_cvt_dwt<<<112, 256, 0, stream>>>(dw_w, dwt);
  k_im2col<<<8192, 256, 0, stream>>>(x, xim);

  k_mgemm<0><<<512, 256, 0, stream>>>(xim, wib, in_b, nullptr, hb, CH_, KIN);
  k_lnb<<<BT, 256, 0, stream>>>(hb, hb, norm_g, norm_b);
  for (int l = 0; l < NL_; ++l) {
    k_dwln<<<dim3(B_, T_ / 32), 256, 0, stream>>>(
        hb, dwt + (size_t)l * 7 * CH_, dw_b + l * CH_,
        ln_g + l * CH_, ln_b + l * CH_, yb);
    k_mgemm<1><<<1536, 256, 0, stream>>>(
        yb, pw1b + (size_t)l * HCH_ * CH_, pw1_b + l * HCH_, nullptr, zb,
        HCH_, CH_);
    k_mgemm<2><<<512, 256, 0, stream>>>(
        zb, pw2b + (size_t)l * CH_ * HCH_, pw2_b + l * CH_, ls + l * CH_, hb,
        CH_, HCH_);
  }
  k_lnb<<<BT, 256, 0, stream>>>(hb, hbL, normLg, normLb);
  k_mgemm<3><<<1024, 256, 0, stream>>>(hbL, owb, out_b, nullptr, o1p, NFFT_, CH_);
  k_zeropad<<<512, 256, 0, stream>>>(o1p);
  k_ovgemm<<<dim3(9, 2, 16), 256, 0, stream>>>(o1p, ovb, o2);
  k_oadd<<<dim3(B_, 4), 256, 0, stream>>>(o2, out);
}

// Round 7
// 889.779 us; speedup vs baseline: 8.4466x; 1.0997x over previous
//
#include <hip/hip_runtime.h>

#define B_    16
#define CIN   100
#define T_    1024
#define CH_   512
#define HCH_  1536
#define NL_   8
#define NFFT_ 1024
#define HOP_  256
#define BT    (B_ * T_)
#define L_    1027
#define OROWS 1032   // padded o1 rows per batch: [4 zero | 1024 data | 4 zero]
#define KIN   704    // im2col K for in-conv (100*7 -> pad 704)

typedef __bf16 bf16x8 __attribute__((ext_vector_type(8)));
typedef float f32x4 __attribute__((ext_vector_type(4)));
typedef short s16x8 __attribute__((ext_vector_type(8)));

__device__ __forceinline__ short f2b(float f) {
  unsigned u = __float_as_uint(f);
  u += 0x7fffu + ((u >> 16) & 1u);
  return (short)(u >> 16);
}
__device__ __forceinline__ float b2f(short s) {
  return __uint_as_float(((unsigned)(unsigned short)s) << 16);
}

// fast tanh-GELU (odd-symmetric, overflow-safe); |err| vs exact-erf ~1.5e-3
__device__ __forceinline__ float fast_gelu(float x) {
  float ax = fabsf(x);
  float z = 0.7978845608f * ax * (1.f + 0.044715f * ax * ax);
  float e = __expf(-2.f * z);
  float th = 1.f - 2.f * e * __builtin_amdgcn_rcpf(1.f + e);  // tanh(z) >= 0
  float g = copysignf(th, x);
  return 0.5f * x * (1.f + g);
}

__device__ __forceinline__ void gl2lds16(const void* g, void* l) {
  __builtin_amdgcn_global_load_lds(
      (__attribute__((address_space(1))) void*)g,
      (__attribute__((address_space(3))) void*)l, 16, 0, 0);
}

// ---------------- weight fp32 -> bf16 (contiguous) --------------------------
__global__ __launch_bounds__(256) void k_cvt(const float* __restrict__ s,
                                             short* __restrict__ d, int n) {
  for (int i = blockIdx.x * 256 + threadIdx.x; i < n; i += gridDim.x * 256)
    d[i] = f2b(s[i]);
}

// ov_w[c][n][k] -> ovb[k][c][n] bf16
__global__ __launch_bounds__(256) void k_cvt_ov(const float* __restrict__ w,
                                                short* __restrict__ d) {
  const int n = 4 * HOP_ * NFFT_;
  for (int i = blockIdx.x * 256 + threadIdx.x; i < n; i += gridDim.x * 256) {
    int k = i >> 18;
    int rem = i & 0x3FFFF;
    int c = rem >> 10, nn = rem & 1023;
    d[i] = f2b(w[((size_t)c * NFFT_ + nn) * 4 + k]);
  }
}

// in_w[c][ci][k] (700 contiguous per c) -> wib[c][704] bf16, pad 0
__global__ __launch_bounds__(256) void k_cvt_inw(const float* __restrict__ w,
                                                 short* __restrict__ d) {
  const int n = CH_ * KIN;
  for (int i = blockIdx.x * 256 + threadIdx.x; i < n; i += gridDim.x * 256) {
    int c = i / KIN, e = i - c * KIN;
    d[i] = (e < 700) ? f2b(w[c * 700 + e]) : (short)0;
  }
}

// dw_w [NL][512][7] fp32 -> dwt [NL][7][512] fp32
__global__ __launch_bounds__(256) void k_cvt_dwt(const float* __restrict__ w,
                                                 float* __restrict__ d) {
  const int n = NL_ * 7 * CH_;
  for (int i = blockIdx.x * 256 + threadIdx.x; i < n; i += gridDim.x * 256) {
    int l = i / (7 * CH_), r = i - l * 7 * CH_;
    int k = r >> 9, c = r & 511;
    d[i] = w[((size_t)l * CH_ + c) * 7 + k];
  }
}

// x[b][ci][t] fp32 -> xim[b*T+t][ci*7+k] = x[b,ci,t+k-3] bf16 (0 pad)
__global__ __launch_bounds__(256) void k_im2col(const float* __restrict__ x,
                                                short* __restrict__ xim) {
  const int total = BT * KIN;
  for (int i = blockIdx.x * 256 + threadIdx.x; i < total; i += gridDim.x * 256) {
    int m = i / KIN, e = i - m * KIN;
    int b = m >> 10, t = m & 1023;
    int ci = e / 7, k = e - ci * 7;
    int tt = t + k - 3;
    float v = (e < 700 && tt >= 0 && tt < T_) ? x[((b * CIN + ci) << 10) + tt] : 0.f;
    xim[i] = f2b(v);
  }
}

// zero the 4+4 pad rows of o1p per batch
__global__ __launch_bounds__(256) void k_zeropad(short* __restrict__ o1p) {
  int i = blockIdx.x * 256 + threadIdx.x;  // 131072
  int b = i >> 13;
  int r8 = (i >> 10) & 7;
  int nn = i & 1023;
  int row = r8 < 4 ? r8 : (OROWS - 8 + r8);
  o1p[((size_t)b * OROWS + row) * NFFT_ + nn] = 0;
}

// ---------------- layernorm bf16 -> bf16 (row of 512) -----------------------
__global__ __launch_bounds__(256) void k_lnb(const short* __restrict__ in,
                                             short* __restrict__ outp,
                                             const float* __restrict__ g,
                                             const float* __restrict__ bta) {
  int row = blockIdx.x, tid = threadIdx.x;
  unsigned u = *reinterpret_cast<const unsigned*>(&in[(size_t)row * CH_ + tid * 2]);
  float v0 = __uint_as_float(u << 16);
  float v1 = __uint_as_float(u & 0xffff0000u);
  float s = v0 + v1, q = v0 * v0 + v1 * v1;
#pragma unroll
  for (int o = 32; o > 0; o >>= 1) { s += __shfl_down(s, o); q += __shfl_down(q, o); }
  __shared__ float sh[8];
  int wid = tid >> 6, lane = tid & 63;
  if (lane == 0) { sh[wid] = s; sh[wid + 4] = q; }
  __syncthreads();
  float S = sh[0] + sh[1] + sh[2] + sh[3];
  float Q = sh[4] + sh[5] + sh[6] + sh[7];
  float mu  = S * (1.f / 512.f);
  float var = Q * (1.f / 512.f) - mu * mu;
  float r = rsqrtf(var + 1e-5f);
  float x0 = (v0 - mu) * r * g[tid * 2]     + bta[tid * 2];
  float x1 = (v1 - mu) * r * g[tid * 2 + 1] + bta[tid * 2 + 1];
  unsigned o = ((unsigned)(unsigned short)f2b(x0)) |
               (((unsigned)(unsigned short)f2b(x1)) << 16);
  *reinterpret_cast<unsigned*>(&outp[(size_t)row * CH_ + tid * 2]) = o;
}

// ---------------- fused depthwise 7-tap + LN, bf16, wave-per-row ------------
__global__ __launch_bounds__(256) void k_dwln(const short* __restrict__ h,
                                              const float* __restrict__ dwt,  // [7][512]
                                              const float* __restrict__ dwb,
                                              const float* __restrict__ g,
                                              const float* __restrict__ bta,
                                              short* __restrict__ yb) {
  int b = blockIdx.x, t0 = blockIdx.y * 32;
  int tid = threadIdx.x, lane = tid & 63, w = tid >> 6;
  __shared__ short hs[38][512];
  for (int e = tid; e < 38 * 64; e += 256) {
    int row = e >> 6, seg = (e & 63) << 3;
    int t = t0 - 3 + row;
    s16x8 v = {};
    if (t >= 0 && t < T_)
      v = *reinterpret_cast<const s16x8*>(&h[((size_t)((b << 10) + t)) * CH_ + seg]);
    *reinterpret_cast<s16x8*>(&hs[row][seg]) = v;
  }
  const int c0 = lane << 3;
  float wk[7][8];
#pragma unroll
  for (int k = 0; k < 7; ++k) {
    f32x4 lo = *reinterpret_cast<const f32x4*>(&dwt[k * CH_ + c0]);
    f32x4 hi = *reinterpret_cast<const f32x4*>(&dwt[k * CH_ + c0 + 4]);
#pragma unroll
    for (int j = 0; j < 4; ++j) { wk[k][j] = lo[j]; wk[k][j + 4] = hi[j]; }
  }
  float bb[8], gg[8], be[8];
  {
    f32x4 a = *reinterpret_cast<const f32x4*>(&dwb[c0]);
    f32x4 b4 = *reinterpret_cast<const f32x4*>(&dwb[c0 + 4]);
    f32x4 c = *reinterpret_cast<const f32x4*>(&g[c0]);
    f32x4 d = *reinterpret_cast<const f32x4*>(&g[c0 + 4]);
    f32x4 e = *reinterpret_cast<const f32x4*>(&bta[c0]);
    f32x4 f = *reinterpret_cast<const f32x4*>(&bta[c0 + 4]);
#pragma unroll
    for (int j = 0; j < 4; ++j) {
      bb[j] = a[j]; bb[j + 4] = b4[j];
      gg[j] = c[j]; gg[j + 4] = d[j];
      be[j] = e[j]; be[j + 4] = f[j];
    }
  }
  __syncthreads();
#pragma unroll
  for (int i = 0; i < 8; ++i) {
    int r = w * 8 + i;
    float acc[8];
#pragma unroll
    for (int j = 0; j < 8; ++j) acc[j] = bb[j];
#pragma unroll
    for (int k = 0; k < 7; ++k) {
      s16x8 hv = *reinterpret_cast<const s16x8*>(&hs[r + k][c0]);
#pragma unroll
      for (int j = 0; j < 8; ++j) acc[j] += b2f(hv[j]) * wk[k][j];
    }
    float s = 0.f, q = 0.f;
#pragma unroll
    for (int j = 0; j < 8; ++j) { s += acc[j]; q += acc[j] * acc[j]; }
#pragma unroll
    for (int o = 32; o > 0; o >>= 1) { s += __shfl_xor(s, o); q += __shfl_xor(q, o); }
    float mu  = s * (1.f / 512.f);
    float var = q * (1.f / 512.f) - mu * mu;
    float rr = rsqrtf(var + 1e-5f);
    s16x8 ov;
#pragma unroll
    for (int j = 0; j < 8; ++j) ov[j] = f2b((acc[j] - mu) * rr * gg[j] + be[j]);
    *reinterpret_cast<s16x8*>(&yb[((size_t)((b << 10) + t0 + r)) * CH_ + c0]) = ov;
  }
}

// ---------------- bf16 MFMA GEMM: C[m,n] = sum_k A[m,k]*Bw[n,k] -------------
// 128x128 tile, BK=64, 4 waves, 2-phase double-buffered pipeline (T3 minimum:
// issue next-tile global_load_lds BEFORE computing current tile; one
// vmcnt(0)+barrier per K-step). XCD-grouped tile mapping; LDS-staged
// coalesced epilogue (16B stores).
// MODE 0: obf = bf16(acc+bias)
// MODE 1: obf = bf16(gelu(acc+bias))
// MODE 2: obf[m][n] = bf16(obf + bf16((acc+bias)*scale))   (residual RMW)
// MODE 3: obf = bf16(acc+bias) at padded o1 rows (b*OROWS+4+t)
template <int MODE>
__global__ __launch_bounds__(256) void k_mgemm(const short* __restrict__ A,
                                               const short* __restrict__ Bw,
                                               const float* __restrict__ bias,
                                               const float* __restrict__ scale,
                                               short* __restrict__ obf,
                                               int N, int K) {
  __shared__ __align__(16) short smem[4 * 128 * 64];   // 64KB: 2 bufs x (A|B)
  const int tid = threadIdx.x;
  const int lane = tid & 63, w = tid >> 6;
  const int id = blockIdx.x;
  const int ny = N >> 7;
  const int g8 = id >> 3;
  const int gq = g8 / ny;
  const int mt = (id & 7) + (gq << 3);
  const int nt_ = g8 - gq * ny;
  const int m0 = mt << 7, n0 = nt_ << 7;
  const int wr = (w >> 1) * 64, wc = (w & 1) * 64;
  f32x4 acc[4][4];
#pragma unroll
  for (int i = 0; i < 4; ++i)
#pragma unroll
    for (int j = 0; j < 4; ++j) acc[i][j] = (f32x4){0.f, 0.f, 0.f, 0.f};

  const short* Ab = A + (size_t)m0 * K;
  const short* Bb = Bw + (size_t)n0 * K;
  int r_[4], kk_[4];
#pragma unroll
  for (int j = 0; j < 4; ++j) {
    int c = tid + j * 256;
    r_[j] = c >> 3;
    kk_[j] = (((c & 7) ^ (r_[j] & 7)) * 8);   // inverse-swizzled source (rule #21)
  }
  const int ar = wr + (lane & 15);
  const int br = wc + (lane & 15);
  const int hi = lane >> 4;
  const int nsteps = K >> 6;

  auto stage = [&](int buf, int k0) {
    short* Sa = smem + buf * 16384;
    short* Sb = Sa + 8192;
#pragma unroll
    for (int j = 0; j < 4; ++j)
      gl2lds16(Ab + (size_t)r_[j] * K + k0 + kk_[j], Sa + (j * 256 + w * 64) * 8);
#pragma unroll
    for (int j = 0; j < 4; ++j)
      gl2lds16(Bb + (size_t)r_[j] * K + k0 + kk_[j], Sb + (j * 256 + w * 64) * 8);
  };

  stage(0, 0);
  asm volatile("s_waitcnt vmcnt(0)" ::: "memory");
  __syncthreads();
  for (int t = 0; t < nsteps; ++t) {
    const int cur = t & 1;
    if (t + 1 < nsteps) stage(cur ^ 1, (t + 1) << 6);   // prefetch next tile
    const short* As = smem + cur * 16384;
    const short* Bs = As + 8192;
#pragma unroll
    for (int ks = 0; ks < 2; ++ks) {
      bf16x8 a[4], b[4];
#pragma unroll
      for (int f = 0; f < 4; ++f) {
        int row = ar + f * 16;
        a[f] = *reinterpret_cast<const bf16x8*>(&As[row * 64 + (((ks * 4 + hi) ^ (row & 7)) * 8)]);
      }
#pragma unroll
      for (int f = 0; f < 4; ++f) {
        int row = br + f * 16;
        b[f] = *reinterpret_cast<const bf16x8*>(&Bs[row * 64 + (((ks * 4 + hi) ^ (row & 7)) * 8)]);
      }
#pragma unroll
      for (int fi = 0; fi < 4; ++fi)
#pragma unroll
        for (int fj = 0; fj < 4; ++fj)
          acc[fi][fj] = __builtin_amdgcn_mfma_f32_16x16x32_bf16(a[fi], b[fj], acc[fi][fj], 0, 0, 0);
    }
    asm volatile("s_waitcnt vmcnt(0)" ::: "memory");
    __syncthreads();
  }
  // ---- epilogue: acc -> LDS (bank-conflict-free) -> coalesced 16B stores ----
  short* Cl = smem;                       // 128x128 shorts = 32KB
  const int colbase = wc + (lane & 15);
#pragma unroll
  for (int fj = 0; fj < 4; ++fj) {
    int cl = colbase + fj * 16;
    int n = n0 + cl;
    float bi = bias[n];
    float sc = (MODE == 2) ? scale[n] : 0.f;
#pragma unroll
    for (int fi = 0; fi < 4; ++fi) {
#pragma unroll
      for (int r = 0; r < 4; ++r) {
        int rl = wr + (hi << 2) + fi * 16 + r;
        float v = acc[fi][fj][r] + bi;
        if (MODE == 1) v = fast_gelu(v);
        if (MODE == 2) v *= sc;
        Cl[rl * 128 + (cl ^ (((rl >> 2) & 3) << 4))] = f2b(v);
      }
    }
  }
  __syncthreads();
  const int cs = (lane & 15) * 8;
#pragma unroll
  for (int it = 0; it < 8; ++it) {
    int rl = w * 32 + it * 4 + (lane >> 4);
    s16x8 v = *reinterpret_cast<const s16x8*>(&Cl[rl * 128 + (cs ^ (((rl >> 2) & 3) << 4))]);
    int m = m0 + rl;
    if (MODE == 2) {
      size_t idx = (size_t)m * N + n0 + cs;
      s16x8 hv = *reinterpret_cast<const s16x8*>(&obf[idx]);
      s16x8 o;
#pragma unroll
      for (int j = 0; j < 8; ++j) o[j] = f2b(b2f(hv[j]) + b2f(v[j]));
      *reinterpret_cast<s16x8*>(&obf[idx]) = o;
    } else if (MODE == 3) {
      int bb = m >> 10, t = m & 1023;
      *reinterpret_cast<s16x8*>(&obf[((size_t)(bb * OROWS + 4 + t)) * NFFT_ + n0 + cs]) = v;
    } else {
      *reinterpret_cast<s16x8*>(&obf[(size_t)m * N + n0 + cs]) = v;
    }
  }
}

// ---------------- overlap conv: A staged once, 4 shifted B-GEMMs ------------
// o2[b][l][c] = sum_{k=0..3} sum_n o1p[b][l+1+k][n] * ovb[k][c][n]
__global__ __launch_bounds__(256) void k_ovgemm(const short* __restrict__ o1p,
                                                const short* __restrict__ ovb,
                                                float* __restrict__ o2) {
  __shared__ __align__(16) short As[136 * 64];   // rows l0+1 .. l0+136
  __shared__ __align__(16) short Bs[128 * 64];
  const int tid = threadIdx.x;
  const int lane = tid & 63, w = tid >> 6;
  const int l0 = blockIdx.x * 128, c0 = blockIdx.y * 128, b = blockIdx.z;
  const int wr = (w >> 1) * 64, wc = (w & 1) * 64;
  f32x4 acc[4][4];
#pragma unroll
  for (int i = 0; i < 4; ++i)
#pragma unroll
    for (int j = 0; j < 4; ++j) acc[i][j] = (f32x4){0.f, 0.f, 0.f, 0.f};

  const short* Ab = o1p + (size_t)b * OROWS * NFFT_;
  const int ar = wr + (lane & 15);
  const int br = wc + (lane & 15);
  const int hi = lane >> 4;
  const int sl_row = lane >> 3;            // 0..7 within a 8-row chunk
  const int sl_j   = lane & 7;             // 16B chunk within row

  for (int k0 = 0; k0 < NFFT_; k0 += 64) {
    // stage A: 17 chunks of 8 rows x 128B (rows shared across all 4 shifts)
    for (int c = w; c < 17; c += 4) {
      int lr = c * 8 + sl_row;
      int gr = l0 + 1 + lr;
      if (gr > OROWS - 1) gr = OROWS - 1;
      int j = sl_j ^ (lr & 7);
      gl2lds16(Ab + (size_t)gr * NFFT_ + k0 + j * 8, As + c * 512);
    }
#pragma unroll
    for (int ksh = 0; ksh < 4; ++ksh) {
      const short* Bb = ovb + ((size_t)(ksh * HOP_ + c0)) * NFFT_;
#pragma unroll
      for (int c = 0; c < 4; ++c) {
        int ch = w * 4 + c;
        int lr = ch * 8 + sl_row;
        int j = sl_j ^ (lr & 7);
        gl2lds16(Bb + (size_t)lr * NFFT_ + k0 + j * 8, Bs + ch * 512);
      }
      asm volatile("s_waitcnt vmcnt(0)" ::: "memory");
      __syncthreads();
#pragma unroll
      for (int ks = 0; ks < 2; ++ks) {
        bf16x8 a[4], bfr[4];
#pragma unroll
        for (int f = 0; f < 4; ++f) {
          int row = ar + f * 16 + ksh;     // shifted A row
          a[f] = *reinterpret_cast<const bf16x8*>(&As[row * 64 + (((ks * 4 + hi) ^ (row & 7)) * 8)]);
        }
#pragma unroll
        for (int f = 0; f < 4; ++f) {
          int row = br + f * 16;
          bfr[f] = *reinterpret_cast<const bf16x8*>(&Bs[row * 64 + (((ks * 4 + hi) ^ (row & 7)) * 8)]);
        }
#pragma unroll
        for (int fi = 0; fi < 4; ++fi)
#pragma unroll
          for (int fj = 0; fj < 4; ++fj)
            acc[fi][fj] = __builtin_amdgcn_mfma_f32_16x16x32_bf16(a[fi], bfr[fj], acc[fi][fj], 0, 0, 0);
      }
      __syncthreads();
    }
  }
  const int lb = l0 + wr + (hi << 2);
  const int cb = c0 + wc + (lane & 15);
#pragma unroll
  for (int fj = 0; fj < 4; ++fj) {
    int c = cb + fj * 16;
#pragma unroll
    for (int fi = 0; fi < 4; ++fi) {
#pragma unroll
      for (int r = 0; r < 4; ++r) {
        int l = lb + fi * 16 + r;
        if (l < L_) o2[((size_t)b * L_ + l) * HOP_ + c] = acc[fi][fj][r];
      }
    }
  }
}

// ---------------- final gather-sum over o2[b][l][c] -------------------------
__global__ __launch_bounds__(256) void k_oadd(const float* __restrict__ o2,
                                              float* __restrict__ out) {
  int b = blockIdx.x;
  int t = blockIdx.y * 256 + threadIdx.x;
  int m = t + 2;
  float s = 0.f;
  for (int c = 0; c < HOP_; ++c) {
    s += o2[((size_t)b * L_ + m) * HOP_ + c];
    m -= 4;
    if (m < 0) m += L_;
  }
  out[b * T_ + t] = s;
}

extern "C" void kernel_launch(void* const* d_in, const int* in_sizes, int n_in,
                              void* d_out, int out_size, void* d_ws, size_t ws_size,
                              hipStream_t stream) {
  const float* x      = (const float*)d_in[0];
  const float* in_w   = (const float*)d_in[1];
  const float* in_b   = (const float*)d_in[2];
  const float* norm_g = (const float*)d_in[3];
  const float* norm_b = (const float*)d_in[4];
  const float* dw_w   = (const float*)d_in[5];
  const float* dw_b   = (const float*)d_in[6];
  const float* ln_g   = (const float*)d_in[7];
  const float* ln_b   = (const float*)d_in[8];
  const float* pw1_w  = (const float*)d_in[9];
  const float* pw1_b  = (const float*)d_in[10];
  const float* pw2_w  = (const float*)d_in[11];
  const float* pw2_b  = (const float*)d_in[12];
  const float* ls     = (const float*)d_in[13];
  const float* normLg = (const float*)d_in[14];
  const float* normLb = (const float*)d_in[15];
  const float* out_w  = (const float*)d_in[16];
  const float* out_b  = (const float*)d_in[17];
  const float* ov_w   = (const float*)d_in[18];
  float* out = (float*)d_out;

  char* p = (char*)d_ws;
  short* hb   = (short*)p; p += (size_t)BT * CH_ * 2;        // 16.78 MB
  short* yb   = (short*)p; p += (size_t)BT * CH_ * 2;        // 16.78 MB
  short* zb   = (short*)p; p += (size_t)BT * HCH_ * 2;       // 50.33 MB
  short* pw1b = (short*)p; p += (size_t)NL_ * HCH_ * CH_ * 2;
  short* pw2b = (short*)p; p += (size_t)NL_ * CH_ * HCH_ * 2;
  short* owb  = (short*)p; p += (size_t)NFFT_ * CH_ * 2;
  short* ovb  = (short*)p; p += (size_t)4 * HOP_ * NFFT_ * 2;
  float* dwt  = (float*)p; p += (size_t)NL_ * 7 * CH_ * 4;
  short* xim  = zb;                        // alias: zb not yet used
  short* wib  = zb + (size_t)BT * KIN;     // fits (23.6 MB < 50.3 MB)
  short* hbL  = yb;                        // alias: yb dead when final LN runs
  short* o1p  = zb;                        // alias: zb dead after layer loop
  float* o2   = (float*)hb;                // spans hb + start of yb; both dead

  k_cvt<<<4096, 256, 0, stream>>>(pw1_w, pw1b, NL_ * HCH_ * CH_);
  k_cvt<<<4096, 256, 0, stream>>>(pw2_w, pw2b, NL_ * CH_ * HCH_);
  k_cvt<<<2048, 256, 0, stream>>>(out_w, owb, NFFT_ * CH_);
  k_cvt_ov<<<4096, 256, 0, stream>>>(ov_w, ovb);
  k_cvt_inw<<<1408, 256, 0, stream>>>(in_w, wib);
  k_cvt_dwt<<<112, 256, 0, stream>>>(dw_w, dwt);
  k_im2col<<<8192, 256, 0, stream>>>(x, xim);

  k_mgemm<0><<<512, 256, 0, stream>>>(xim, wib, in_b, nullptr, hb, CH_, KIN);
  k_lnb<<<BT, 256, 0, stream>>>(hb, hb, norm_g, norm_b);
  for (int l = 0; l < NL_; ++l) {
    k_dwln<<<dim3(B_, T_ / 32), 256, 0, stream>>>(
        hb, dwt + (size_t)l * 7 * CH_, dw_b + l * CH_,
        ln_g + l * CH_, ln_b + l * CH_, yb);
    k_mgemm<1><<<1536, 256, 0, stream>>>(
        yb, pw1b + (size_t)l * HCH_ * CH_, pw1_b + l * HCH_, nullptr, zb,
        HCH_, CH_);
    k_mgemm<2><<<512, 256, 0, stream>>>(
        zb, pw2b + (size_t)l * CH_ * HCH_, pw2_b + l * CH_, ls + l * CH_, hb,
        CH_, HCH_);
  }
  k_lnb<<<BT, 256, 0, stream>>>(hb, hbL, normLg, normLb);
  k_mgemm<3><<<1024, 256, 0, stream>>>(hbL, owb, out_b, nullptr, o1p, NFFT_, CH_);
  k_zeropad<<<512, 256, 0, stream>>>(o1p);
  k_ovgemm<<<dim3(9, 2, 16), 256, 0, stream>>>(o1p, ovb, o2);
  k_oadd<<<dim3(B_, 4), 256, 0, stream>>>(o2, out);
}

// Round 9
// 885.733 us; speedup vs baseline: 8.4852x; 1.0046x over previous
//
#include <hip/hip_runtime.h>

#define B_    16
#define CIN   100
#define T_    1024
#define CH_   512
#define HCH_  1536
#define NL_   8
#define NFFT_ 1024
#define HOP_  256
#define BT    (B_ * T_)
#define L_    1027
#define OROWS 1032   // padded o1 rows per batch: [4 zero | 1024 data | 4 zero]
#define KIN   704    // im2col K for in-conv (100*7 -> pad 704)

typedef __bf16 bf16x8 __attribute__((ext_vector_type(8)));
typedef float f32x4 __attribute__((ext_vector_type(4)));
typedef short s16x8 __attribute__((ext_vector_type(8)));
typedef short s16x4 __attribute__((ext_vector_type(4)));

__device__ __forceinline__ short f2b(float f) {
  unsigned u = __float_as_uint(f);
  u += 0x7fffu + ((u >> 16) & 1u);
  return (short)(u >> 16);
}
__device__ __forceinline__ float b2f(short s) {
  return __uint_as_float(((unsigned)(unsigned short)s) << 16);
}

// fast tanh-GELU (odd-symmetric, overflow-safe); |err| vs exact-erf ~1.5e-3
__device__ __forceinline__ float fast_gelu(float x) {
  float ax = fabsf(x);
  float z = 0.7978845608f * ax * (1.f + 0.044715f * ax * ax);
  float e = __expf(-2.f * z);
  float th = 1.f - 2.f * e * __builtin_amdgcn_rcpf(1.f + e);  // tanh(z) >= 0
  float g = copysignf(th, x);
  return 0.5f * x * (1.f + g);
}

__device__ __forceinline__ void gl2lds16(const void* g, void* l) {
  __builtin_amdgcn_global_load_lds(
      (__attribute__((address_space(1))) void*)g,
      (__attribute__((address_space(3))) void*)l, 16, 0, 0);
}

// ---------------- weight fp32 -> bf16, vectorized (n % 4 == 0) --------------
__global__ __launch_bounds__(256) void k_cvt4(const float* __restrict__ s,
                                              short* __restrict__ d, int n4) {
  for (int i = blockIdx.x * 256 + threadIdx.x; i < n4; i += gridDim.x * 256) {
    f32x4 v = *reinterpret_cast<const f32x4*>(&s[i * 4]);
    s16x4 o = {f2b(v[0]), f2b(v[1]), f2b(v[2]), f2b(v[3])};
    *reinterpret_cast<s16x4*>(&d[i * 4]) = o;
  }
}

// ov_w[c][n][k] -> ovb[k][c][n] bf16 (coalesced read 16B, 4 coalesced planes)
__global__ __launch_bounds__(256) void k_cvt_ov(const float* __restrict__ w,
                                                short* __restrict__ d) {
  const int n = HOP_ * NFFT_;   // (c,n) pairs
  for (int i = blockIdx.x * 256 + threadIdx.x; i < n; i += gridDim.x * 256) {
    f32x4 v = *reinterpret_cast<const f32x4*>(&w[(size_t)i * 4]);
#pragma unroll
    for (int k = 0; k < 4; ++k) d[(size_t)k * n + i] = f2b(v[k]);
  }
}

// in_w[c][ci][k] (700 contiguous per c) -> wib[c][704] bf16, pad 0
__global__ __launch_bounds__(256) void k_cvt_inw(const float* __restrict__ w,
                                                 short* __restrict__ d) {
  const int n = CH_ * KIN;
  for (int i = blockIdx.x * 256 + threadIdx.x; i < n; i += gridDim.x * 256) {
    int c = i / KIN, e = i - c * KIN;
    d[i] = (e < 700) ? f2b(w[c * 700 + e]) : (short)0;
  }
}

// dw_w [NL][512][7] fp32 -> dwt [NL][7][512] fp32
__global__ __launch_bounds__(256) void k_cvt_dwt(const float* __restrict__ w,
                                                 float* __restrict__ d) {
  const int n = NL_ * 7 * CH_;
  for (int i = blockIdx.x * 256 + threadIdx.x; i < n; i += gridDim.x * 256) {
    int l = i / (7 * CH_), r = i - l * 7 * CH_;
    int k = r >> 9, c = r & 511;
    d[i] = w[((size_t)l * CH_ + c) * 7 + k];
  }
}

// x[b][ci][t] fp32 -> xim[b*T+t][ci*7+k] = x[b,ci,t+k-3] bf16 (0 pad)
__global__ __launch_bounds__(256) void k_im2col(const float* __restrict__ x,
                                                short* __restrict__ xim) {
  const int total = BT * KIN;
  for (int i = blockIdx.x * 256 + threadIdx.x; i < total; i += gridDim.x * 256) {
    int m = i / KIN, e = i - m * KIN;
    int b = m >> 10, t = m & 1023;
    int ci = e / 7, k = e - ci * 7;
    int tt = t + k - 3;
    float v = (e < 700 && tt >= 0 && tt < T_) ? x[((b * CIN + ci) << 10) + tt] : 0.f;
    xim[i] = f2b(v);
  }
}

// zero the 4+4 pad rows of o1p per batch
__global__ __launch_bounds__(256) void k_zeropad(short* __restrict__ o1p) {
  int i = blockIdx.x * 256 + threadIdx.x;  // 131072
  int b = i >> 13;
  int r8 = (i >> 10) & 7;
  int nn = i & 1023;
  int row = r8 < 4 ? r8 : (OROWS - 8 + r8);
  o1p[((size_t)b * OROWS + row) * NFFT_ + nn] = 0;
}

// ---------------- layernorm bf16 -> bf16 (row of 512) -----------------------
__global__ __launch_bounds__(256) void k_lnb(const short* __restrict__ in,
                                             short* __restrict__ outp,
                                             const float* __restrict__ g,
                                             const float* __restrict__ bta) {
  int row = blockIdx.x, tid = threadIdx.x;
  unsigned u = *reinterpret_cast<const unsigned*>(&in[(size_t)row * CH_ + tid * 2]);
  float v0 = __uint_as_float(u << 16);
  float v1 = __uint_as_float(u & 0xffff0000u);
  float s = v0 + v1, q = v0 * v0 + v1 * v1;
#pragma unroll
  for (int o = 32; o > 0; o >>= 1) { s += __shfl_down(s, o); q += __shfl_down(q, o); }
  __shared__ float sh[8];
  int wid = tid >> 6, lane = tid & 63;
  if (lane == 0) { sh[wid] = s; sh[wid + 4] = q; }
  __syncthreads();
  float S = sh[0] + sh[1] + sh[2] + sh[3];
  float Q = sh[4] + sh[5] + sh[6] + sh[7];
  float mu  = S * (1.f / 512.f);
  float var = Q * (1.f / 512.f) - mu * mu;
  float r = rsqrtf(var + 1e-5f);
  float x0 = (v0 - mu) * r * g[tid * 2]     + bta[tid * 2];
  float x1 = (v1 - mu) * r * g[tid * 2 + 1] + bta[tid * 2 + 1];
  unsigned o = ((unsigned)(unsigned short)f2b(x0)) |
               (((unsigned)(unsigned short)f2b(x1)) << 16);
  *reinterpret_cast<unsigned*>(&outp[(size_t)row * CH_ + tid * 2]) = o;
}

// ---------------- fused depthwise 7-tap + LN, bf16, wave-per-row ------------
__global__ __launch_bounds__(256) void k_dwln(const short* __restrict__ h,
                                              const float* __restrict__ dwt,  // [7][512]
                                              const float* __restrict__ dwb,
                                              const float* __restrict__ g,
                                              const float* __restrict__ bta,
                                              short* __restrict__ yb) {
  int b = blockIdx.x, t0 = blockIdx.y * 32;
  int tid = threadIdx.x, lane = tid & 63, w = tid >> 6;
  __shared__ short hs[38][512];
  for (int e = tid; e < 38 * 64; e += 256) {
    int row = e >> 6, seg = (e & 63) << 3;
    int t = t0 - 3 + row;
    s16x8 v = {};
    if (t >= 0 && t < T_)
      v = *reinterpret_cast<const s16x8*>(&h[((size_t)((b << 10) + t)) * CH_ + seg]);
    *reinterpret_cast<s16x8*>(&hs[row][seg]) = v;
  }
  const int c0 = lane << 3;
  float wk[7][8];
#pragma unroll
  for (int k = 0; k < 7; ++k) {
    f32x4 lo = *reinterpret_cast<const f32x4*>(&dwt[k * CH_ + c0]);
    f32x4 hi = *reinterpret_cast<const f32x4*>(&dwt[k * CH_ + c0 + 4]);
#pragma unroll
    for (int j = 0; j < 4; ++j) { wk[k][j] = lo[j]; wk[k][j + 4] = hi[j]; }
  }
  float bb[8], gg[8], be[8];
  {
    f32x4 a = *reinterpret_cast<const f32x4*>(&dwb[c0]);
    f32x4 b4 = *reinterpret_cast<const f32x4*>(&dwb[c0 + 4]);
    f32x4 c = *reinterpret_cast<const f32x4*>(&g[c0]);
    f32x4 d = *reinterpret_cast<const f32x4*>(&g[c0 + 4]);
    f32x4 e = *reinterpret_cast<const f32x4*>(&bta[c0]);
    f32x4 f = *reinterpret_cast<const f32x4*>(&bta[c0 + 4]);
#pragma unroll
    for (int j = 0; j < 4; ++j) {
      bb[j] = a[j]; bb[j + 4] = b4[j];
      gg[j] = c[j]; gg[j + 4] = d[j];
      be[j] = e[j]; be[j + 4] = f[j];
    }
  }
  __syncthreads();
#pragma unroll
  for (int i = 0; i < 8; ++i) {
    int r = w * 8 + i;
    float acc[8];
#pragma unroll
    for (int j = 0; j < 8; ++j) acc[j] = bb[j];
#pragma unroll
    for (int k = 0; k < 7; ++k) {
      s16x8 hv = *reinterpret_cast<const s16x8*>(&hs[r + k][c0]);
#pragma unroll
      for (int j = 0; j < 8; ++j) acc[j] += b2f(hv[j]) * wk[k][j];
    }
    float s = 0.f, q = 0.f;
#pragma unroll
    for (int j = 0; j < 8; ++j) { s += acc[j]; q += acc[j] * acc[j]; }
#pragma unroll
    for (int o = 32; o > 0; o >>= 1) { s += __shfl_xor(s, o); q += __shfl_xor(q, o); }
    float mu  = s * (1.f / 512.f);
    float var = q * (1.f / 512.f) - mu * mu;
    float rr = rsqrtf(var + 1e-5f);
    s16x8 ov;
#pragma unroll
    for (int j = 0; j < 8; ++j) ov[j] = f2b((acc[j] - mu) * rr * gg[j] + be[j]);
    *reinterpret_cast<s16x8*>(&yb[((size_t)((b << 10) + t0 + r)) * CH_ + c0]) = ov;
  }
}

// ---------------- bf16 MFMA GEMM: C[m,n] = sum_k A[m,k]*Bw[n,k] -------------
// 128x128 tile, BK=64, 4 waves, 2-phase double-buffered pipeline.
// MODE 0: obf = bf16(acc+bias)
// MODE 1: obf = bf16(gelu(acc+bias))
// MODE 2: obf[m][n] = bf16(obf + bf16((acc+bias)*scale))   (residual RMW)
// MODE 3: obf = bf16(acc+bias) at padded o1 rows (b*OROWS+4+t)
template <int MODE>
__global__ __launch_bounds__(256) void k_mgemm(const short* __restrict__ A,
                                               const short* __restrict__ Bw,
                                               const float* __restrict__ bias,
                                               const float* __restrict__ scale,
                                               short* __restrict__ obf,
                                               int N, int K) {
  __shared__ __align__(16) short smem[4 * 128 * 64];   // 64KB: 2 bufs x (A|B)
  const int tid = threadIdx.x;
  const int lane = tid & 63, w = tid >> 6;
  const int id = blockIdx.x;
  const int ny = N >> 7;
  const int g8 = id >> 3;
  const int gq = g8 / ny;
  const int mt = (id & 7) + (gq << 3);
  const int nt_ = g8 - gq * ny;
  const int m0 = mt << 7, n0 = nt_ << 7;
  const int wr = (w >> 1) * 64, wc = (w & 1) * 64;
  f32x4 acc[4][4];
#pragma unroll
  for (int i = 0; i < 4; ++i)
#pragma unroll
    for (int j = 0; j < 4; ++j) acc[i][j] = (f32x4){0.f, 0.f, 0.f, 0.f};

  const short* Ab = A + (size_t)m0 * K;
  const short* Bb = Bw + (size_t)n0 * K;
  int r_[4], kk_[4];
#pragma unroll
  for (int j = 0; j < 4; ++j) {
    int c = tid + j * 256;
    r_[j] = c >> 3;
    kk_[j] = (((c & 7) ^ (r_[j] & 7)) * 8);   // inverse-swizzled source (rule #21)
  }
  const int ar = wr + (lane & 15);
  const int br = wc + (lane & 15);
  const int hi = lane >> 4;
  const int nsteps = K >> 6;

  auto stage = [&](int buf, int k0) {
    short* Sa = smem + buf * 16384;
    short* Sb = Sa + 8192;
#pragma unroll
    for (int j = 0; j < 4; ++j)
      gl2lds16(Ab + (size_t)r_[j] * K + k0 + kk_[j], Sa + (j * 256 + w * 64) * 8);
#pragma unroll
    for (int j = 0; j < 4; ++j)
      gl2lds16(Bb + (size_t)r_[j] * K + k0 + kk_[j], Sb + (j * 256 + w * 64) * 8);
  };

  stage(0, 0);
  asm volatile("s_waitcnt vmcnt(0)" ::: "memory");
  __syncthreads();
  for (int t = 0; t < nsteps; ++t) {
    const int cur = t & 1;
    if (t + 1 < nsteps) stage(cur ^ 1, (t + 1) << 6);   // prefetch next tile
    const short* As = smem + cur * 16384;
    const short* Bs = As + 8192;
#pragma unroll
    for (int ks = 0; ks < 2; ++ks) {
      bf16x8 a[4], b[4];
#pragma unroll
      for (int f = 0; f < 4; ++f) {
        int row = ar + f * 16;
        a[f] = *reinterpret_cast<const bf16x8*>(&As[row * 64 + (((ks * 4 + hi) ^ (row & 7)) * 8)]);
      }
#pragma unroll
      for (int f = 0; f < 4; ++f) {
        int row = br + f * 16;
        b[f] = *reinterpret_cast<const bf16x8*>(&Bs[row * 64 + (((ks * 4 + hi) ^ (row & 7)) * 8)]);
      }
#pragma unroll
      for (int fi = 0; fi < 4; ++fi)
#pragma unroll
        for (int fj = 0; fj < 4; ++fj)
          acc[fi][fj] = __builtin_amdgcn_mfma_f32_16x16x32_bf16(a[fi], b[fj], acc[fi][fj], 0, 0, 0);
    }
    asm volatile("s_waitcnt vmcnt(0)" ::: "memory");
    __syncthreads();
  }
  // ---- epilogue: acc -> LDS (bank-conflict-free) -> coalesced 16B stores ----
  short* Cl = smem;                       // 128x128 shorts = 32KB
  const int colbase = wc + (lane & 15);
#pragma unroll
  for (int fj = 0; fj < 4; ++fj) {
    int cl = colbase + fj * 16;
    int n = n0 + cl;
    float bi = bias[n];
    float sc = (MODE == 2) ? scale[n] : 0.f;
#pragma unroll
    for (int fi = 0; fi < 4; ++fi) {
#pragma unroll
      for (int r = 0; r < 4; ++r) {
        int rl = wr + (hi << 2) + fi * 16 + r;
        float v = acc[fi][fj][r] + bi;
        if (MODE == 1) v = fast_gelu(v);
        if (MODE == 2) v *= sc;
        Cl[rl * 128 + (cl ^ (((rl >> 2) & 3) << 4))] = f2b(v);
      }
    }
  }
  __syncthreads();
  const int cs = (lane & 15) * 8;
#pragma unroll
  for (int it = 0; it < 8; ++it) {
    int rl = w * 32 + it * 4 + (lane >> 4);
    s16x8 v = *reinterpret_cast<const s16x8*>(&Cl[rl * 128 + (cs ^ (((rl >> 2) & 3) << 4))]);
    int m = m0 + rl;
    if (MODE == 2) {
      size_t idx = (size_t)m * N + n0 + cs;
      s16x8 hv = *reinterpret_cast<const s16x8*>(&obf[idx]);
      s16x8 o;
#pragma unroll
      for (int j = 0; j < 8; ++j) o[j] = f2b(b2f(hv[j]) + b2f(v[j]));
      *reinterpret_cast<s16x8*>(&obf[idx]) = o;
    } else if (MODE == 3) {
      int bb = m >> 10, t = m & 1023;
      *reinterpret_cast<s16x8*>(&obf[((size_t)(bb * OROWS + 4 + t)) * NFFT_ + n0 + cs]) = v;
    } else {
      *reinterpret_cast<s16x8*>(&obf[(size_t)m * N + n0 + cs]) = v;
    }
  }
}

// ---------------- overlap conv: 128(l)x64(c) tiles, A+B double-buffered -----
// o2[b][l][c] = sum_{k=0..3} sum_n o1p[b][l+1+k][n] * ovb[k][c][n]
// 64 phases (16 k0-steps x 4 ksh); A staged per k0 (dbuf), B per phase (dbuf).
__global__ __launch_bounds__(256) void k_ovgemm(const short* __restrict__ o1p,
                                                const short* __restrict__ ovb,
                                                float* __restrict__ o2) {
  __shared__ __align__(16) short As2[2][136 * 64];   // 2 x 17.0 KB
  __shared__ __align__(16) short Bs2[2][64 * 64];    // 2 x 8 KB
  const int tid = threadIdx.x;
  const int lane = tid & 63, w = tid >> 6;
  const int l0 = blockIdx.x * 128, c0 = blockIdx.y * 64, b = blockIdx.z;
  const int wr = (w >> 1) * 64, wc = (w & 1) * 32;
  f32x4 acc[4][2];
#pragma unroll
  for (int i = 0; i < 4; ++i)
#pragma unroll
    for (int j = 0; j < 2; ++j) acc[i][j] = (f32x4){0.f, 0.f, 0.f, 0.f};

  const short* Ab = o1p + (size_t)b * OROWS * NFFT_;
  const int ar = wr + (lane & 15);
  const int br = wc + (lane & 15);
  const int hi = lane >> 4;
  const int sl_row = lane >> 3;            // 0..7 within an 8-row chunk group
  const int sl_j   = lane & 7;             // 16B chunk within row
  int br_[2], bk_[2];
#pragma unroll
  for (int j = 0; j < 2; ++j) {
    int c = tid + j * 256;
    br_[j] = c >> 3;
    bk_[j] = ((c & 7) ^ (br_[j] & 7)) * 8;
  }

  auto stageA = [&](int buf, int k0) {
    for (int cg = w; cg < 17; cg += 4) {
      int lr = cg * 8 + sl_row;
      int gr = l0 + 1 + lr;
      if (gr > OROWS - 1) gr = OROWS - 1;   // clamp into zero pad
      int j = sl_j ^ (lr & 7);
      gl2lds16(Ab + (size_t)gr * NFFT_ + k0 + j * 8, &As2[buf][cg * 512]);
    }
  };
  auto stageB = [&](int buf, int k0, int ksh) {
    const short* Bb = ovb + ((size_t)(ksh * HOP_ + c0)) * NFFT_;
#pragma unroll
    for (int j = 0; j < 2; ++j)
      gl2lds16(Bb + (size_t)br_[j] * NFFT_ + k0 + bk_[j],
               &Bs2[buf][(j * 256 + w * 64) * 8]);
  };

  int ab = 0, bb = 0;
  stageA(0, 0);
  stageB(0, 0, 0);
  asm volatile("s_waitcnt vmcnt(0)" ::: "memory");
  __syncthreads();
  for (int t = 0; t < 64; ++t) {            // 16 k0-steps x 4 ksh
    const int ksh = t & 3;
    const int nt = t + 1;
    if (nt < 64) {
      int nk0 = (nt >> 2) << 6;
      if ((nt & 3) == 0) stageA(ab ^ 1, nk0);
      stageB(bb ^ 1, nk0, nt & 3);
    }
    const short* As = As2[ab];
    const short* Bs = Bs2[bb];
#pragma unroll
    for (int ks = 0; ks < 2; ++ks) {
      bf16x8 a[4], bfr[2];
#pragma unroll
      for (int f = 0; f < 4; ++f) {
        int row = ar + f * 16 + ksh;       // shifted A row
        a[f] = *reinterpret_cast<const bf16x8*>(&As[row * 64 + (((ks * 4 + hi) ^ (row & 7)) * 8)]);
      }
#pragma unroll
      for (int f = 0; f < 2; ++f) {
        int row = br + f * 16;
        bfr[f] = *reinterpret_cast<const bf16x8*>(&Bs[row * 64 + (((ks * 4 + hi) ^ (row & 7)) * 8)]);
      }
#pragma unroll
      for (int fi = 0; fi < 4; ++fi)
#pragma unroll
        for (int fj = 0; fj < 2; ++fj)
          acc[fi][fj] = __builtin_amdgcn_mfma_f32_16x16x32_bf16(a[fi], bfr[fj], acc[fi][fj], 0, 0, 0);
    }
    asm volatile("s_waitcnt vmcnt(0)" ::: "memory");
    __syncthreads();
    bb ^= 1;
    if (ksh == 3) ab ^= 1;
  }
  const int lb = l0 + wr + (hi << 2);
  const int cb = c0 + wc + (lane & 15);
#pragma unroll
  for (int fj = 0; fj < 2; ++fj) {
    int c = cb + fj * 16;
#pragma unroll
    for (int fi = 0; fi < 4; ++fi) {
#pragma unroll
      for (int r = 0; r < 4; ++r) {
        int l = lb + fi * 16 + r;
        if (l < L_) o2[((size_t)b * L_ + l) * HOP_ + c] = acc[fi][fj][r];
      }
    }
  }
}

// ---------------- final gather-sum over o2[b][l][c] -------------------------
__global__ __launch_bounds__(256) void k_oadd(const float* __restrict__ o2,
                                              float* __restrict__ out) {
  int b = blockIdx.x;
  int t = blockIdx.y * 256 + threadIdx.x;
  int m = t + 2;
  float s = 0.f;
  for (int c = 0; c < HOP_; ++c) {
    s += o2[((size_t)b * L_ + m) * HOP_ + c];
    m -= 4;
    if (m < 0) m += L_;
  }
  out[b * T_ + t] = s;
}

extern "C" void kernel_launch(void* const* d_in, const int* in_sizes, int n_in,
                              void* d_out, int out_size, void* d_ws, size_t ws_size,
                              hipStream_t stream) {
  const float* x      = (const float*)d_in[0];
  const float* in_w   = (const float*)d_in[1];
  const float* in_b   = (const float*)d_in[2];
  const float* norm_g = (const float*)d_in[3];
  const float* norm_b = (const float*)d_in[4];
  const float* dw_w   = (const float*)d_in[5];
  const float* dw_b   = (const float*)d_in[6];
  const float* ln_g   = (const float*)d_in[7];
  const float* ln_b   = (const float*)d_in[8];
  const float* pw1_w  = (const float*)d_in[9];
  const float* pw1_b  = (const float*)d_in[10];
  const float* pw2_w  = (const float*)d_in[11];
  const float* pw2_b  = (const float*)d_in[12];
  const float* ls     = (const float*)d_in[13];
  const float* normLg = (const float*)d_in[14];
  const float* normLb = (const float*)d_in[15];
  const float* out_w  = (const float*)d_in[16];
  const float* out_b  = (const float*)d_in[17];
  const float* ov_w   = (const float*)d_in[18];
  float* out = (float*)d_out;

  char* p = (char*)d_ws;
  short* hb   = (short*)p; p += (size_t)BT * CH_ * 2;        // 16.78 MB
  short* yb   = (short*)p; p += (size_t)BT * CH_ * 2;        // 16.78 MB
  short* zb   = (short*)p; p += (size_t)BT * HCH_ * 2;       // 50.33 MB
  short* pw1b = (short*)p; p += (size_t)NL_ * HCH_ * CH_ * 2;
  short* pw2b = (short*)p; p += (size_t)NL_ * CH_ * HCH_ * 2;
  short* owb  = (short*)p; p += (size_t)NFFT_ * CH_ * 2;
  short* ovb  = (short*)p; p += (size_t)4 * HOP_ * NFFT_ * 2;
  float* dwt  = (float*)p; p += (size_t)NL_ * 7 * CH_ * 4;
  short* xim  = zb;                        // alias: zb not yet used
  short* wib  = zb + (size_t)BT * KIN;     // fits (23.6 MB < 50.3 MB)
  short* hbL  = yb;                        // alias: yb dead when final LN runs
  short* o1p  = zb;                        // alias: zb dead after layer loop
  float* o2   = (float*)hb;                // spans hb + start of yb; both dead

  k_cvt4<<<4096, 256, 0, stream>>>(pw1_w, pw1b, NL_ * HCH_ * CH_ / 4);
  k_cvt4<<<4096, 256, 0, stream>>>(pw2_w, pw2b, NL_ * CH_ * HCH_ / 4);
  k_cvt4<<<512, 256, 0, stream>>>(out_w, owb, NFFT_ * CH_ / 4);
  k_cvt_ov<<<1024, 256, 0, stream>>>(ov_w, ovb);
  k_cvt_inw<<<1408, 256, 0, stream>>>(in_w, wib);
  k_cvt_dwt<<<112, 256, 0, stream>>>(dw_w, dwt);
  k_im2col<<<8192, 256, 0, stream>>>(x, xim);

  k_mgemm<0><<<512, 256, 0, stream>>>(xim, wib, in_b, nullptr, hb, CH_, KIN);
  k_lnb<<<BT, 256, 0, stream>>>(hb, hb, norm_g, norm_b);
  for (int l = 0; l < NL_; ++l) {
    k_dwln<<<dim3(B_, T_ / 32), 256, 0, stream>>>(
        hb, dwt + (size_t)l * 7 * CH_, dw_b + l * CH_,
        ln_g + l * CH_, ln_b + l * CH_, yb);
    k_mgemm<1><<<1536, 256, 0, stream>>>(
        yb, pw1b + (size_t)l * HCH_ * CH_, pw1_b + l * HCH_, nullptr, zb,
        HCH_, CH_);
    k_mgemm<2><<<512, 256, 0, stream>>>(
        zb, pw2b + (size_t)l * CH_ * HCH_, pw2_b + l * CH_, ls + l * CH_, hb,
        CH_, HCH_);
  }
  k_lnb<<<BT, 256, 0, stream>>>(hb, hbL, normLg, normLb);
  k_mgemm<3><<<1024, 256, 0, stream>>>(hbL, owb, out_b, nullptr, o1p, NFFT_, CH_);
  k_zeropad<<<512, 256, 0, stream>>>(o1p);
  k_ovgemm<<<dim3(9, 4, 16), 256, 0, stream>>>(o1p, ovb, o2);
  k_oadd<<<dim3(B_, 4), 256, 0, stream>>>(o2, out);
}